// Round 2
// baseline (4792.679 us; speedup 1.0000x reference)
//
#include <hip/hip_runtime.h>
#include <hip/hip_bf16.h>
#include <stdint.h>

#define DEV __device__ __forceinline__

typedef __bf16 bf16x8 __attribute__((ext_vector_type(8)));
typedef float f32x4 __attribute__((ext_vector_type(4)));

constexpr int kB = 4, kT = 4096, kC = 2048, kH = 32, kN = 64;
constexpr int kM = kB * kT; // 16384

// ---------- bf16 helpers (raw ushort storage everywhere) ----------
DEV float bfu2f(unsigned short u) {
  union { uint32_t i; float f; } x; x.i = ((uint32_t)u) << 16; return x.f;
}
DEV unsigned short f2bfu(float f) {
  union { float f; uint32_t i; } x; x.f = f;
  uint32_t r = x.i + 0x7FFFu + ((x.i >> 16) & 1u);
  return (unsigned short)(r >> 16);
}

// ---------- async global->LDS (16B per lane, wave-uniform LDS base) ----------
DEV void gld16(const void* g, void* l) {
  __builtin_amdgcn_global_load_lds(
      (const __attribute__((address_space(1))) void*)g,
      (__attribute__((address_space(3))) void*)l, 16, 0, 0);
}

// ---------- generic transpose + fp32->bf16:  out[c][r] = bf16(in[r][c]) ----------
__global__ __launch_bounds__(256) void trans_bf16(
    const float* __restrict__ in, unsigned short* __restrict__ out, int R, int Cn) {
  __shared__ __attribute__((aligned(16))) unsigned short tile[64][65];
  const int t = threadIdx.x;
  const int r0 = blockIdx.y * 64, c0 = blockIdx.x * 64;
  const int lr = t >> 6, lc = t & 63;
#pragma unroll
  for (int i = 0; i < 16; i++) {
    int rr = lr + i * 4;
    int gr = r0 + rr, gc = c0 + lc;
    if (gr < R && gc < Cn) tile[rr][lc] = f2bfu(in[(size_t)gr * Cn + gc]);
  }
  __syncthreads();
#pragma unroll
  for (int i = 0; i < 16; i++) {
    int cc = lr + i * 4;
    int gc = c0 + cc, gr = r0 + lc;
    if (gc < Cn && gr < R) out[(size_t)gc * R + gr] = tile[lc][cc];
  }
}

// ---------- prep: xxx = bf16(x + (shift(x)-x)*maa_x), lx copy ----------
__global__ __launch_bounds__(256) void prep_x2(
    const float* __restrict__ x, const float* __restrict__ shift,
    const float* __restrict__ maax,
    unsigned short* __restrict__ xxx, float* __restrict__ lx) {
  size_t i4 = ((size_t)blockIdx.x * 256 + threadIdx.x) * 4;
  int c = (int)(i4 & (kC - 1));
  size_t bt = i4 >> 11;           // /C
  int tt = (int)(bt & (kT - 1));
  int b = (int)(bt >> 12);        // /T
  float4 xv = *(const float4*)(x + i4);
  float4 pv = (tt == 0) ? *(const float4*)(shift + (size_t)b * kC + c)
                        : *(const float4*)(x + i4 - kC);
  float4 mx = *(const float4*)(maax + c);
  ushort4 o4;
  o4.x = f2bfu(xv.x + (pv.x - xv.x) * mx.x);
  o4.y = f2bfu(xv.y + (pv.y - xv.y) * mx.y);
  o4.z = f2bfu(xv.z + (pv.z - xv.z) * mx.z);
  o4.w = f2bfu(xv.w + (pv.w - xv.w) * mx.w);
  *(ushort4*)(xxx + i4) = o4;
  if (tt == kT - 1) *(float4*)(lx + (size_t)b * kC + c) = xv;
}

// ---------- bf16 MFMA GEMM:  C[M][N] = A[M][K] * Bt[N][K]^T, fp32 acc ----------
enum { E_F32 = 0, E_BF16 = 1, E_TANH = 2, E_SILU = 3, E_DECAY = 4 };

template <int BM, int BN, int EPI>
__global__ __launch_bounds__(256) void gemm_k(
    const unsigned short* __restrict__ A, const unsigned short* __restrict__ Bt,
    void* __restrict__ Cout, const float* __restrict__ aux, int M, int N, int K) {
  constexpr int WGM = (BM == 128 && BN == 128) ? 2 : (BM == 64 ? 2 : 4);
  constexpr int WGN = 4 / WGM;
  constexpr int WM = BM / WGM, WN = BN / WGN;
  constexpr int WR = WM / 16, WC = WN / 16;
  __shared__ __attribute__((aligned(16))) unsigned short As[BM * 32];
  __shared__ __attribute__((aligned(16))) unsigned short Bs[BN * 32];
  const int t = threadIdx.x, wid = t >> 6, l = t & 63;
  const int m0 = blockIdx.x * BM, n0 = blockIdx.y * BN;
  const int wm0 = (wid / WGN) * WM, wn0 = (wid % WGN) * WN;
  f32x4 acc[WR][WC];
#pragma unroll
  for (int i = 0; i < WR; i++)
#pragma unroll
    for (int j = 0; j < WC; j++) acc[i][j] = f32x4{0.f, 0.f, 0.f, 0.f};

  const int rowS = t >> 2, cbS = (t & 3) * 16;
  const char* Ab = (const char*)A;
  const char* Bb = (const char*)Bt;
  const int aoff = (wm0 + (l & 15)) * 32 + (l >> 4) * 8;
  const int boff = (wn0 + (l & 15)) * 32 + (l >> 4) * 8;

  for (int kt = 0; kt < K; kt += 32) {
#pragma unroll
    for (int ia = 0; ia < BM / 64; ia++)
      gld16(Ab + ((size_t)(m0 + ia * 64 + rowS) * K + kt) * 2 + cbS,
            (char*)As + ia * 4096 + wid * 1024);
    if constexpr (BN >= 64) {
#pragma unroll
      for (int ib = 0; ib < BN / 64; ib++)
        gld16(Bb + ((size_t)(n0 + ib * 64 + rowS) * K + kt) * 2 + cbS,
              (char*)Bs + ib * 4096 + wid * 1024);
    } else {
      if (t < BN * 4)
        gld16(Bb + ((size_t)(n0 + rowS) * K + kt) * 2 + cbS,
              (char*)Bs + wid * 1024);
    }
    __syncthreads();
    bf16x8 af[WR], bfv[WC];
#pragma unroll
    for (int mi = 0; mi < WR; mi++) af[mi] = *(const bf16x8*)(&As[aoff + mi * 512]);
#pragma unroll
    for (int ni = 0; ni < WC; ni++) bfv[ni] = *(const bf16x8*)(&Bs[boff + ni * 512]);
#pragma unroll
    for (int mi = 0; mi < WR; mi++)
#pragma unroll
      for (int ni = 0; ni < WC; ni++)
        acc[mi][ni] = __builtin_amdgcn_mfma_f32_16x16x32_bf16(af[mi], bfv[ni], acc[mi][ni], 0, 0, 0);
    __syncthreads();
  }

#pragma unroll
  for (int mi = 0; mi < WR; mi++) {
#pragma unroll
    for (int ni = 0; ni < WC; ni++) {
      int row = m0 + wm0 + mi * 16 + (l >> 4) * 4;
      int col = n0 + wn0 + ni * 16 + (l & 15);
#pragma unroll
      for (int j = 0; j < 4; j++) {
        float v = acc[mi][ni][j];
        size_t idx = (size_t)(row + j) * N + col;
        if constexpr (EPI == E_F32) ((float*)Cout)[idx] = v;
        else if constexpr (EPI == E_BF16) ((unsigned short*)Cout)[idx] = f2bfu(v);
        else if constexpr (EPI == E_TANH) ((unsigned short*)Cout)[idx] = f2bfu(tanhf(v));
        else if constexpr (EPI == E_SILU) ((unsigned short*)Cout)[idx] = f2bfu(v / (1.f + expf(-v)));
        else if constexpr (EPI == E_DECAY) {
          float w = v + aux[col];
          ((float*)Cout)[idx] = expf(-expf(w));
        }
      }
    }
  }
}

// ---------- single-feature mix:  m = t5[:,f*32:(f+1)*32] @ w2t[:,f*32:(f+1)*32]^T
//            xout = bf16( x + (shift(x)-x) * (maa + m) )
__global__ __launch_bounds__(256) void mixf_k(
    const unsigned short* __restrict__ t5, const unsigned short* __restrict__ w2t,
    const float* __restrict__ x, const float* __restrict__ shift,
    const float* __restrict__ maa, unsigned short* __restrict__ xout, int f) {
  __shared__ __attribute__((aligned(16))) unsigned short As[64 * 32];
  __shared__ __attribute__((aligned(16))) unsigned short Bs[64 * 32];
  const int t = threadIdx.x, wid = t >> 6, l = t & 63;
  const int m0 = blockIdx.x * 64, n0 = blockIdx.y * 64;
  const int wm0 = (wid >> 1) * 32, wn0 = (wid & 1) * 32;
  const int rowS = t >> 2, cbS = (t & 3) * 16;
  const int aoff = (wm0 + (l & 15)) * 32 + (l >> 4) * 8;
  const int boff = (wn0 + (l & 15)) * 32 + (l >> 4) * 8;

  gld16((const char*)t5 + ((size_t)(m0 + rowS) * 160 + f * 32) * 2 + cbS, (char*)As + wid * 1024);
  gld16((const char*)w2t + ((size_t)(n0 + rowS) * 160 + f * 32) * 2 + cbS, (char*)Bs + wid * 1024);
  __syncthreads();
  bf16x8 a0 = *(const bf16x8*)(&As[aoff]), a1 = *(const bf16x8*)(&As[aoff + 512]);
  bf16x8 b0 = *(const bf16x8*)(&Bs[boff]), b1 = *(const bf16x8*)(&Bs[boff + 512]);
  f32x4 acc[2][2];
  acc[0][0] = f32x4{0.f, 0.f, 0.f, 0.f}; acc[0][1] = f32x4{0.f, 0.f, 0.f, 0.f};
  acc[1][0] = f32x4{0.f, 0.f, 0.f, 0.f}; acc[1][1] = f32x4{0.f, 0.f, 0.f, 0.f};
  acc[0][0] = __builtin_amdgcn_mfma_f32_16x16x32_bf16(a0, b0, acc[0][0], 0, 0, 0);
  acc[0][1] = __builtin_amdgcn_mfma_f32_16x16x32_bf16(a0, b1, acc[0][1], 0, 0, 0);
  acc[1][0] = __builtin_amdgcn_mfma_f32_16x16x32_bf16(a1, b0, acc[1][0], 0, 0, 0);
  acc[1][1] = __builtin_amdgcn_mfma_f32_16x16x32_bf16(a1, b1, acc[1][1], 0, 0, 0);

#pragma unroll
  for (int mi = 0; mi < 2; mi++)
#pragma unroll
    for (int ni = 0; ni < 2; ni++) {
      int row = m0 + wm0 + mi * 16 + (l >> 4) * 4;
      int col = n0 + wn0 + ni * 16 + (l & 15);
      float mv = maa[col];
#pragma unroll
      for (int j = 0; j < 4; j++) {
        int rrow = row + j;
        int tt = rrow & (kT - 1);
        size_t idx = (size_t)rrow * kC + col;
        float xv = x[idx];
        float pv = (tt == 0) ? shift[(size_t)(rrow >> 12) * kC + col] : x[idx - kC];
        xout[idx] = f2bfu(xv + (pv - xv) * (mv + acc[mi][ni][j]));
      }
    }
}

// ---------- WKV sequential scan: 1 block per (b,h), 4 waves split k 4x16 ----------
__global__ __launch_bounds__(256) void wkv_k(
    const unsigned short* __restrict__ rb, const unsigned short* __restrict__ kb,
    const unsigned short* __restrict__ vb, const float* __restrict__ ed,
    const float* __restrict__ uf, const float* __restrict__ s0,
    unsigned short* __restrict__ o, float* __restrict__ sOut) {
  const int bh = blockIdx.x, h = bh & 31, b = bh >> 5;
  const int t = threadIdx.x, wid = t >> 6, j = t & 63;
  const float u = uf[h * 64 + j];
  float S[16];
  const size_t sbase = (size_t)bh * 4096;
#pragma unroll
  for (int q = 0; q < 16; q++) S[q] = s0[sbase + (size_t)(wid * 16 + q) * 64 + j];
  __shared__ __attribute__((aligned(16))) float4 rkd[4][16];
  __shared__ __attribute__((aligned(16))) float po[4][64];
  size_t base = (size_t)b * kT * kC + h * 64 + j;
  float rr = bfu2f(rb[base]), kk = bfu2f(kb[base]), dd = ed[base], vv = bfu2f(vb[base]);
  const bool writer = ((j >> 4) == wid);
  const int wslot = j & 15;
  for (int tt = 0; tt < kT; ++tt) {
    float ap = rr * u * kk;
#pragma unroll
    for (int m = 1; m < 64; m <<= 1) ap += __shfl_xor(ap, m, 64);
    if (writer) rkd[wid][wslot] = make_float4(rr, kk, dd, 0.f);
    float vc = vv;
    float rn = 0.f, kn = 0.f, dn = 0.f, vn = 0.f;
    if (tt + 1 < kT) {
      size_t nidx = base + (size_t)(tt + 1) * kC;
      rn = bfu2f(rb[nidx]); kn = bfu2f(kb[nidx]); dn = ed[nidx]; vn = bfu2f(vb[nidx]);
    }
    __syncthreads();
    float op = 0.f;
#pragma unroll
    for (int q = 0; q < 16; q++) {
      float4 f4 = rkd[wid][q];
      op += f4.x * S[q];
      S[q] = f4.z * S[q] + f4.y * vc;
    }
    po[wid][j] = op;
    __syncthreads();
    if (wid == 0) o[base + (size_t)tt * kC] = f2bfu(po[0][j] + po[1][j] + po[2][j] + po[3][j] + ap * vc);
    rr = rn; kk = kn; dd = dn; vv = vn;
  }
#pragma unroll
  for (int q = 0; q < 16; q++) sOut[sbase + (size_t)(wid * 16 + q) * 64 + j] = S[q];
}

// ---------- GroupNorm over N=64 per (b,t,h), times g, -> bf16 ----------
__global__ __launch_bounds__(256) void gn_k(
    const unsigned short* __restrict__ o, const unsigned short* __restrict__ gb,
    const float* __restrict__ gnw, const float* __restrict__ gnb,
    unsigned short* __restrict__ y) {
  int gi = blockIdx.x * 4 + (threadIdx.x >> 6);
  int j = threadIdx.x & 63;
  int bt = gi >> 5, h = gi & 31;
  size_t idx = (size_t)bt * kC + h * 64 + j;
  float val = bfu2f(o[idx]);
  float s = val, s2 = val * val;
#pragma unroll
  for (int m = 1; m < 64; m <<= 1) {
    s += __shfl_xor(s, m, 64);
    s2 += __shfl_xor(s2, m, 64);
  }
  float mu = s * 0.015625f;
  float var = s2 * 0.015625f - mu * mu;
  float rs = rsqrtf(var + 6.4e-4f);
  float on = (val - mu) * rs * gnw[h * 64 + j] + gnb[h * 64 + j];
  y[idx] = f2bfu(on * bfu2f(gb[idx]));
}

// ---------- workspace layout (peak ~433 MiB) ----------
constexpr size_t SZW     = (size_t)2048 * 2048 * 2;              // 8 MiB bf16 weight
constexpr size_t OFF_WRT = 0;
constexpr size_t OFF_WKT = 1 * SZW;
constexpr size_t OFF_WVT = 2 * SZW;
constexpr size_t OFF_WGT = 3 * SZW;
constexpr size_t OFF_WOT = 4 * SZW;
constexpr size_t OFF_W1T = 5 * SZW;                              // [160][2048] bf16
constexpr size_t OFF_W2T = OFF_W1T + (size_t)160 * 2048 * 2;     // [2048][160] bf16
constexpr size_t OFF_TD1 = OFF_W2T + (size_t)2048 * 160 * 2;     // [64][2048] bf16
constexpr size_t OFF_TD2 = OFF_TD1 + (size_t)64 * 2048 * 2;      // [2048][64] bf16
constexpr size_t OFF_T5  = OFF_TD2 + (size_t)2048 * 64 * 2;      // [M][160] bf16
constexpr size_t OFF_DT  = OFF_T5 + (size_t)kM * 160 * 2;        // [M][64] bf16 (dtmp)
constexpr size_t OFF_EDEC= OFF_DT + (size_t)kM * 64 * 2;         // [M][C] f32 edec; later xg bf16
constexpr size_t OFF_XMIX= OFF_EDEC + (size_t)kM * kC * 4;       // xxx/xw/xk/xv/xr bf16; later o bf16
constexpr size_t OFF_R   = OFF_XMIX + (size_t)kM * kC * 2;       // r bf16; later g bf16
constexpr size_t OFF_K   = OFF_R + (size_t)kM * kC * 2;          // k bf16; later y bf16
constexpr size_t OFF_V   = OFF_K + (size_t)kM * kC * 2;          // v bf16

extern "C" void kernel_launch(void* const* d_in, const int* in_sizes, int n_in,
                              void* d_out, int out_size, void* d_ws, size_t ws_size,
                              hipStream_t stream) {
  const float* x     = (const float*)d_in[0];
  const float* shift = (const float*)d_in[1];
  const float* s0    = (const float*)d_in[2];
  const float* maax  = (const float*)d_in[3];
  const float* maaw  = (const float*)d_in[4];
  const float* maak  = (const float*)d_in[5];
  const float* maav  = (const float*)d_in[6];
  const float* maar  = (const float*)d_in[7];
  const float* maag  = (const float*)d_in[8];
  const float* w1    = (const float*)d_in[9];
  const float* w2    = (const float*)d_in[10];
  const float* tdec  = (const float*)d_in[11];
  const float* tdw1  = (const float*)d_in[12];
  const float* tdw2  = (const float*)d_in[13];
  const float* faaaa = (const float*)d_in[14];
  const float* Wr    = (const float*)d_in[15];
  const float* Wk    = (const float*)d_in[16];
  const float* Wv    = (const float*)d_in[17];
  const float* Wg    = (const float*)d_in[18];
  const float* Wo    = (const float*)d_in[19];
  const float* gnw   = (const float*)d_in[20];
  const float* gnb   = (const float*)d_in[21];

  char* ws = (char*)d_ws;
  unsigned short* Wrt  = (unsigned short*)(ws + OFF_WRT);
  unsigned short* Wkt  = (unsigned short*)(ws + OFF_WKT);
  unsigned short* Wvt  = (unsigned short*)(ws + OFF_WVT);
  unsigned short* Wgt  = (unsigned short*)(ws + OFF_WGT);
  unsigned short* Wot  = (unsigned short*)(ws + OFF_WOT);
  unsigned short* w1t  = (unsigned short*)(ws + OFF_W1T);
  unsigned short* w2t  = (unsigned short*)(ws + OFF_W2T);
  unsigned short* td1t = (unsigned short*)(ws + OFF_TD1);
  unsigned short* td2t = (unsigned short*)(ws + OFF_TD2);
  unsigned short* t5   = (unsigned short*)(ws + OFF_T5);
  unsigned short* dtmp = (unsigned short*)(ws + OFF_DT);
  float*          edec = (float*)(ws + OFF_EDEC);
  unsigned short* xg   = (unsigned short*)(ws + OFF_EDEC); // after edec dead
  unsigned short* xmix = (unsigned short*)(ws + OFF_XMIX);
  unsigned short* obf  = (unsigned short*)(ws + OFF_XMIX); // after xmix dead
  unsigned short* rbb  = (unsigned short*)(ws + OFF_R);
  unsigned short* gbb  = (unsigned short*)(ws + OFF_R);    // after r dead
  unsigned short* kbb  = (unsigned short*)(ws + OFF_K);
  unsigned short* ybuf = (unsigned short*)(ws + OFF_K);    // after k dead
  unsigned short* vbb  = (unsigned short*)(ws + OFF_V);

  float* outp  = (float*)d_out;
  float* lx    = outp + (size_t)kM * kC;
  float* stOut = lx + (size_t)kB * kC;

  dim3 blk(256);

  // weight prep (transpose to [N][K] bf16)
  trans_bf16<<<dim3(32, 32), blk, 0, stream>>>(Wr, Wrt, 2048, 2048);
  trans_bf16<<<dim3(32, 32), blk, 0, stream>>>(Wk, Wkt, 2048, 2048);
  trans_bf16<<<dim3(32, 32), blk, 0, stream>>>(Wv, Wvt, 2048, 2048);
  trans_bf16<<<dim3(32, 32), blk, 0, stream>>>(Wg, Wgt, 2048, 2048);
  trans_bf16<<<dim3(32, 32), blk, 0, stream>>>(Wo, Wot, 2048, 2048);
  trans_bf16<<<dim3(3, 32), blk, 0, stream>>>(w1, w1t, 2048, 160);
  trans_bf16<<<dim3(1, 32), blk, 0, stream>>>(tdw1, td1t, 2048, 64);
  trans_bf16<<<dim3(32, 1), blk, 0, stream>>>(tdw2, td2t, 64, 2048);
  trans_bf16<<<dim3(32, 3), blk, 0, stream>>>(w2, w2t, 160, 2048);

  // token shift + maa_x mix (+ lx output)
  prep_x2<<<dim3(kM * kC / 4 / 256), blk, 0, stream>>>(x, shift, maax, xmix, lx);

  // t5 = tanh(xxx @ w1)  -> [M][160]
  gemm_k<128, 32, E_TANH><<<dim3(kM / 128, 5), blk, 0, stream>>>(xmix, w1t, t5, nullptr, kM, 160, 2048);

  dim3 mgrid(kM / 64, kC / 64);

  // decay path: xw -> dtmp = tanh(xw @ tdw1); edec = exp(-exp(dtmp @ tdw2 + time_decay))
  mixf_k<<<mgrid, blk, 0, stream>>>(t5, w2t, x, shift, maaw, xmix, 0);
  gemm_k<64, 64, E_TANH><<<dim3(kM / 64, 1), blk, 0, stream>>>(xmix, td1t, dtmp, nullptr, kM, 64, 2048);
  gemm_k<128, 128, E_DECAY><<<dim3(kM / 128, 16), blk, 0, stream>>>(dtmp, td2t, edec, tdec, kM, 2048, 64);

  // k, v, r projections (sequential reuse of xmix)
  mixf_k<<<mgrid, blk, 0, stream>>>(t5, w2t, x, shift, maak, xmix, 1);
  gemm_k<128, 128, E_BF16><<<dim3(kM / 128, 16), blk, 0, stream>>>(xmix, Wkt, kbb, nullptr, kM, 2048, 2048);
  mixf_k<<<mgrid, blk, 0, stream>>>(t5, w2t, x, shift, maav, xmix, 2);
  gemm_k<128, 128, E_BF16><<<dim3(kM / 128, 16), blk, 0, stream>>>(xmix, Wvt, vbb, nullptr, kM, 2048, 2048);
  mixf_k<<<mgrid, blk, 0, stream>>>(t5, w2t, x, shift, maar, xmix, 3);
  gemm_k<128, 128, E_BF16><<<dim3(kM / 128, 16), blk, 0, stream>>>(xmix, Wrt, rbb, nullptr, kM, 2048, 2048);

  // sequential WKV scan -> o (bf16, reuses xmix region), final state
  wkv_k<<<dim3(kB * kH), blk, 0, stream>>>(rbb, kbb, vbb, edec, faaaa, s0, obf, stOut);

  // g path (after wkv so xg reuses edec region, g reuses r region)
  mixf_k<<<mgrid, blk, 0, stream>>>(t5, w2t, x, shift, maag, xg, 4);
  gemm_k<128, 128, E_SILU><<<dim3(kM / 128, 16), blk, 0, stream>>>(xg, Wgt, gbb, nullptr, kM, 2048, 2048);

  // groupnorm * g -> bf16 (y reuses k region)
  gn_k<<<dim3(kM * kH / 4), blk, 0, stream>>>(obf, gbb, gnw, gnb, ybuf);

  // out = y @ Wo -> d_out
  gemm_k<128, 128, E_F32><<<dim3(kM / 128, 16), blk, 0, stream>>>(ybuf, Wot, outp, nullptr, kM, 2048, 2048);
}

// Round 3
// 2105.841 us; speedup vs baseline: 2.2759x; 2.2759x over previous
//
#include <hip/hip_runtime.h>
#include <hip/hip_bf16.h>
#include <stdint.h>

#define DEV __device__ __forceinline__

typedef __bf16 bf16x8 __attribute__((ext_vector_type(8)));
typedef float f32x4 __attribute__((ext_vector_type(4)));
typedef unsigned short u16x8 __attribute__((ext_vector_type(8)));

constexpr int kB = 4, kT = 4096, kC = 2048, kH = 32, kN = 64;
constexpr int kM = kB * kT; // 16384

// ---------- bf16 helpers (raw ushort storage everywhere) ----------
DEV float bfu2f(unsigned short u) {
  union { uint32_t i; float f; } x; x.i = ((uint32_t)u) << 16; return x.f;
}
DEV unsigned short f2bfu(float f) {
  union { float f; uint32_t i; } x; x.f = f;
  uint32_t r = x.i + 0x7FFFu + ((x.i >> 16) & 1u);
  return (unsigned short)(r >> 16);
}

// ---------- async global->LDS (16B per lane, wave-uniform LDS base) ----------
DEV void gld16(const void* g, void* l) {
  __builtin_amdgcn_global_load_lds(
      (const __attribute__((address_space(1))) void*)g,
      (__attribute__((address_space(3))) void*)l, 16, 0, 0);
}

// ---------- generic transpose + fp32->bf16:  out[c][r] = bf16(in[r][c]) ----------
__global__ __launch_bounds__(256) void trans_bf16(
    const float* __restrict__ in, unsigned short* __restrict__ out, int R, int Cn) {
  __shared__ __attribute__((aligned(16))) unsigned short tile[64][65];
  const int t = threadIdx.x;
  const int r0 = blockIdx.y * 64, c0 = blockIdx.x * 64;
  const int lr = t >> 6, lc = t & 63;
#pragma unroll
  for (int i = 0; i < 16; i++) {
    int rr = lr + i * 4;
    int gr = r0 + rr, gc = c0 + lc;
    if (gr < R && gc < Cn) tile[rr][lc] = f2bfu(in[(size_t)gr * Cn + gc]);
  }
  __syncthreads();
#pragma unroll
  for (int i = 0; i < 16; i++) {
    int cc = lr + i * 4;
    int gc = c0 + cc, gr = r0 + lc;
    if (gc < Cn && gr < R) out[(size_t)gc * R + gr] = tile[lc][cc];
  }
}

// ---------- prep: xxx = bf16(x + (shift(x)-x)*maa_x), lx copy ----------
__global__ __launch_bounds__(256) void prep_x2(
    const float* __restrict__ x, const float* __restrict__ shift,
    const float* __restrict__ maax,
    unsigned short* __restrict__ xxx, float* __restrict__ lx) {
  size_t i4 = ((size_t)blockIdx.x * 256 + threadIdx.x) * 4;
  int c = (int)(i4 & (kC - 1));
  size_t bt = i4 >> 11;           // /C
  int tt = (int)(bt & (kT - 1));
  int b = (int)(bt >> 12);        // /T
  float4 xv = *(const float4*)(x + i4);
  float4 pv = (tt == 0) ? *(const float4*)(shift + (size_t)b * kC + c)
                        : *(const float4*)(x + i4 - kC);
  float4 mx = *(const float4*)(maax + c);
  ushort4 o4;
  o4.x = f2bfu(xv.x + (pv.x - xv.x) * mx.x);
  o4.y = f2bfu(xv.y + (pv.y - xv.y) * mx.y);
  o4.z = f2bfu(xv.z + (pv.z - xv.z) * mx.z);
  o4.w = f2bfu(xv.w + (pv.w - xv.w) * mx.w);
  *(ushort4*)(xxx + i4) = o4;
  if (tt == kT - 1) *(float4*)(lx + (size_t)b * kC + c) = xv;
}

// ---------- bf16 MFMA GEMM:  C[M][N] = A[M][K] * Bt[N][K]^T, fp32 acc ----------
enum { E_F32 = 0, E_BF16 = 1, E_TANH = 2, E_SILU = 3, E_DECAY = 4 };

template <int BM, int BN, int EPI>
__global__ __launch_bounds__(256) void gemm_k(
    const unsigned short* __restrict__ A, const unsigned short* __restrict__ Bt,
    void* __restrict__ Cout, const float* __restrict__ aux, int M, int N, int K) {
  constexpr int WGM = (BM == 128 && BN == 128) ? 2 : (BM == 64 ? 2 : 4);
  constexpr int WGN = 4 / WGM;
  constexpr int WM = BM / WGM, WN = BN / WGN;
  constexpr int WR = WM / 16, WC = WN / 16;
  __shared__ __attribute__((aligned(16))) unsigned short As[BM * 32];
  __shared__ __attribute__((aligned(16))) unsigned short Bs[BN * 32];
  const int t = threadIdx.x, wid = t >> 6, l = t & 63;
  const int m0 = blockIdx.x * BM, n0 = blockIdx.y * BN;
  const int wm0 = (wid / WGN) * WM, wn0 = (wid % WGN) * WN;
  f32x4 acc[WR][WC];
#pragma unroll
  for (int i = 0; i < WR; i++)
#pragma unroll
    for (int j = 0; j < WC; j++) acc[i][j] = f32x4{0.f, 0.f, 0.f, 0.f};

  const int rowS = t >> 2, cbS = (t & 3) * 16;
  const char* Ab = (const char*)A;
  const char* Bb = (const char*)Bt;
  const int aoff = (wm0 + (l & 15)) * 32 + (l >> 4) * 8;
  const int boff = (wn0 + (l & 15)) * 32 + (l >> 4) * 8;

  for (int kt = 0; kt < K; kt += 32) {
#pragma unroll
    for (int ia = 0; ia < BM / 64; ia++)
      gld16(Ab + ((size_t)(m0 + ia * 64 + rowS) * K + kt) * 2 + cbS,
            (char*)As + ia * 4096 + wid * 1024);
    if constexpr (BN >= 64) {
#pragma unroll
      for (int ib = 0; ib < BN / 64; ib++)
        gld16(Bb + ((size_t)(n0 + ib * 64 + rowS) * K + kt) * 2 + cbS,
              (char*)Bs + ib * 4096 + wid * 1024);
    } else {
      if (t < BN * 4)
        gld16(Bb + ((size_t)(n0 + rowS) * K + kt) * 2 + cbS,
              (char*)Bs + wid * 1024);
    }
    __syncthreads();
    bf16x8 af[WR], bfv[WC];
#pragma unroll
    for (int mi = 0; mi < WR; mi++) af[mi] = *(const bf16x8*)(&As[aoff + mi * 512]);
#pragma unroll
    for (int ni = 0; ni < WC; ni++) bfv[ni] = *(const bf16x8*)(&Bs[boff + ni * 512]);
#pragma unroll
    for (int mi = 0; mi < WR; mi++)
#pragma unroll
      for (int ni = 0; ni < WC; ni++)
        acc[mi][ni] = __builtin_amdgcn_mfma_f32_16x16x32_bf16(af[mi], bfv[ni], acc[mi][ni], 0, 0, 0);
    __syncthreads();
  }

#pragma unroll
  for (int mi = 0; mi < WR; mi++) {
#pragma unroll
    for (int ni = 0; ni < WC; ni++) {
      int row = m0 + wm0 + mi * 16 + (l >> 4) * 4;
      int col = n0 + wn0 + ni * 16 + (l & 15);
#pragma unroll
      for (int j = 0; j < 4; j++) {
        float v = acc[mi][ni][j];
        size_t idx = (size_t)(row + j) * N + col;
        if constexpr (EPI == E_F32) ((float*)Cout)[idx] = v;
        else if constexpr (EPI == E_BF16) ((unsigned short*)Cout)[idx] = f2bfu(v);
        else if constexpr (EPI == E_TANH) ((unsigned short*)Cout)[idx] = f2bfu(tanhf(v));
        else if constexpr (EPI == E_SILU) ((unsigned short*)Cout)[idx] = f2bfu(v / (1.f + expf(-v)));
        else if constexpr (EPI == E_DECAY) {
          float w = v + aux[col];
          ((float*)Cout)[idx] = expf(-expf(w));
        }
      }
    }
  }
}

// ---------- single-feature mix:  m = t5[:,f*32:(f+1)*32] @ w2t[:,f*32:(f+1)*32]^T
//            xout = bf16( x + (shift(x)-x) * (maa + m) )
__global__ __launch_bounds__(256) void mixf_k(
    const unsigned short* __restrict__ t5, const unsigned short* __restrict__ w2t,
    const float* __restrict__ x, const float* __restrict__ shift,
    const float* __restrict__ maa, unsigned short* __restrict__ xout, int f) {
  __shared__ __attribute__((aligned(16))) unsigned short As[64 * 32];
  __shared__ __attribute__((aligned(16))) unsigned short Bs[64 * 32];
  const int t = threadIdx.x, wid = t >> 6, l = t & 63;
  const int m0 = blockIdx.x * 64, n0 = blockIdx.y * 64;
  const int wm0 = (wid >> 1) * 32, wn0 = (wid & 1) * 32;
  const int rowS = t >> 2, cbS = (t & 3) * 16;
  const int aoff = (wm0 + (l & 15)) * 32 + (l >> 4) * 8;
  const int boff = (wn0 + (l & 15)) * 32 + (l >> 4) * 8;

  gld16((const char*)t5 + ((size_t)(m0 + rowS) * 160 + f * 32) * 2 + cbS, (char*)As + wid * 1024);
  gld16((const char*)w2t + ((size_t)(n0 + rowS) * 160 + f * 32) * 2 + cbS, (char*)Bs + wid * 1024);
  __syncthreads();
  bf16x8 a0 = *(const bf16x8*)(&As[aoff]), a1 = *(const bf16x8*)(&As[aoff + 512]);
  bf16x8 b0 = *(const bf16x8*)(&Bs[boff]), b1 = *(const bf16x8*)(&Bs[boff + 512]);
  f32x4 acc[2][2];
  acc[0][0] = f32x4{0.f, 0.f, 0.f, 0.f}; acc[0][1] = f32x4{0.f, 0.f, 0.f, 0.f};
  acc[1][0] = f32x4{0.f, 0.f, 0.f, 0.f}; acc[1][1] = f32x4{0.f, 0.f, 0.f, 0.f};
  acc[0][0] = __builtin_amdgcn_mfma_f32_16x16x32_bf16(a0, b0, acc[0][0], 0, 0, 0);
  acc[0][1] = __builtin_amdgcn_mfma_f32_16x16x32_bf16(a0, b1, acc[0][1], 0, 0, 0);
  acc[1][0] = __builtin_amdgcn_mfma_f32_16x16x32_bf16(a1, b0, acc[1][0], 0, 0, 0);
  acc[1][1] = __builtin_amdgcn_mfma_f32_16x16x32_bf16(a1, b1, acc[1][1], 0, 0, 0);

#pragma unroll
  for (int mi = 0; mi < 2; mi++)
#pragma unroll
    for (int ni = 0; ni < 2; ni++) {
      int row = m0 + wm0 + mi * 16 + (l >> 4) * 4;
      int col = n0 + wn0 + ni * 16 + (l & 15);
      float mv = maa[col];
#pragma unroll
      for (int j = 0; j < 4; j++) {
        int rrow = row + j;
        int tt = rrow & (kT - 1);
        size_t idx = (size_t)rrow * kC + col;
        float xv = x[idx];
        float pv = (tt == 0) ? shift[(size_t)(rrow >> 12) * kC + col] : x[idx - kC];
        xout[idx] = f2bfu(xv + (pv - xv) * (mv + acc[mi][ni][j]));
      }
    }
}

// ---------- chunked WKV: 1 block per (b,h), L=64 chunks, MFMA intra/cross ----------
// swizzled byte offset within a [64-row][128B] bf16 LDS tile
DEV int swzb(int row, int byteoff) { return (row << 7) + (byteoff ^ ((row & 7) << 4)); }

__global__ __launch_bounds__(256) void wkv_chunk_k(
    const unsigned short* __restrict__ rb, const unsigned short* __restrict__ kb,
    const unsigned short* __restrict__ vb, const float* __restrict__ ed,
    const float* __restrict__ uf, const float* __restrict__ s0,
    unsigned short* __restrict__ o, float* __restrict__ sOut) {
  const int bh = blockIdx.x, h = bh & 31, b = bh >> 5;
  const int tid = threadIdx.x, w = tid >> 6, l = tid & 63;
  __shared__ __attribute__((aligned(16))) unsigned short RQ[4096];   // [t][k] swz bf16
  __shared__ __attribute__((aligned(16))) unsigned short KQsk[4096]; // [s][k] swz
  __shared__ __attribute__((aligned(16))) unsigned short KQks[4096]; // [k][s] swz
  __shared__ __attribute__((aligned(16))) unsigned short Vt[4096];   // [v][s] swz
  __shared__ __attribute__((aligned(16))) unsigned short Pl[4096];   // [t][s] swz
  __shared__ __attribute__((aligned(16))) unsigned short S0T[4096];  // [v][k] swz
  __shared__ __attribute__((aligned(16))) float Sf[64][68];          // fp32 master state
  __shared__ float segp[4][64];
  __shared__ float DLs[64];
  __shared__ float diag[64];

  const float uu = uf[h * 64 + l];

  // ---- init state: fp32 master + bf16 transposed copy ----
  {
    int k0 = tid >> 2, vs = (tid & 3) << 4;
    const float* sp = s0 + (size_t)bh * 4096 + (size_t)k0 * 64 + vs;
#pragma unroll
    for (int q = 0; q < 4; q++) {
      float4 f4 = ((const float4*)sp)[q];
      int v = vs + q * 4;
      Sf[k0][v + 0] = f4.x; Sf[k0][v + 1] = f4.y; Sf[k0][v + 2] = f4.z; Sf[k0][v + 3] = f4.w;
      *(unsigned short*)((char*)S0T + swzb(v + 0, k0 * 2)) = f2bfu(f4.x);
      *(unsigned short*)((char*)S0T + swzb(v + 1, k0 * 2)) = f2bfu(f4.y);
      *(unsigned short*)((char*)S0T + swzb(v + 2, k0 * 2)) = f2bfu(f4.z);
      *(unsigned short*)((char*)S0T + swzb(v + 3, k0 * 2)) = f2bfu(f4.w);
    }
  }
  __syncthreads();

  const int fr = l & 15, fq = l >> 4;
  float rv[16], kv[16], dv[16], vv[16];

  // preload chunk 0 (lane = channel, wave = t-segment)
  {
    size_t g = ((size_t)b * kT + w * 16) * kC + h * 64 + l;
#pragma unroll
    for (int i = 0; i < 16; i++) {
      rv[i] = bfu2f(rb[g]); kv[i] = bfu2f(kb[g]); vv[i] = bfu2f(vb[g]); dv[i] = ed[g];
      g += kC;
    }
  }

  for (int ch = 0; ch < 64; ++ch) {
    // ---- phase A: cumprods, RQ/KQ/Vt tiles, diag ----
    float p = 1.f;
#pragma unroll
    for (int i = 0; i < 16; i++) p *= dv[i];
    segp[w][l] = p;
    __syncthreads();
    float pre = 1.f;
    if (w > 0) pre *= segp[0][l];
    if (w > 1) pre *= segp[1][l];
    if (w > 2) pre *= segp[2][l];
    if (w == 3) DLs[l] = pre * p;

    unsigned short kqrow[16], vtrow[16];
    float run = pre;
#pragma unroll
    for (int i = 0; i < 16; i++) {
      int t = w * 16 + i;
      float rq = rv[i] * run;
      run *= dv[i];
      float kq = kv[i] / run;
      *(unsigned short*)((char*)RQ + swzb(t, l * 2)) = f2bfu(rq);
      unsigned short kqu = f2bfu(kq);
      *(unsigned short*)((char*)KQsk + swzb(t, l * 2)) = kqu;
      kqrow[i] = kqu;
      vtrow[i] = f2bfu(vv[i]);
    }
    {
      u16x8 q0, q1, v0, v1;
#pragma unroll
      for (int j = 0; j < 8; j++) { q0[j] = kqrow[j]; q1[j] = kqrow[j + 8]; v0[j] = vtrow[j]; v1[j] = vtrow[j + 8]; }
      *(u16x8*)((char*)KQks + swzb(l, w * 32)) = q0;
      *(u16x8*)((char*)KQks + swzb(l, w * 32 + 16)) = q1;
      *(u16x8*)((char*)Vt + swzb(l, w * 32)) = v0;
      *(u16x8*)((char*)Vt + swzb(l, w * 32 + 16)) = v1;
    }
#pragma unroll
    for (int i = 0; i < 16; i++) {
      float dsv = rv[i] * uu * kv[i];
#pragma unroll
      for (int m = 1; m < 64; m <<= 1) dsv += __shfl_xor(dsv, m, 64);
      if (l == 0) diag[w * 16 + i] = dsv;
    }

    // ---- issue next chunk's loads (latency hides under MFMA phases) ----
    if (ch < 63) {
      size_t g = ((size_t)b * kT + (ch + 1) * 64 + w * 16) * kC + h * 64 + l;
#pragma unroll
      for (int i = 0; i < 16; i++) {
        rv[i] = bfu2f(rb[g]); kv[i] = bfu2f(kb[g]); vv[i] = bfu2f(vb[g]); dv[i] = ed[g];
        g += kC;
      }
    }
    __syncthreads();

    // ---- phase C: P = strict_lower(RQ @ KQ^T), diag = u-term ----
    bf16x8 a0 = *(const bf16x8*)((const char*)RQ + swzb(w * 16 + fr, fq * 16));
    bf16x8 a1 = *(const bf16x8*)((const char*)RQ + swzb(w * 16 + fr, fq * 16 + 64));
    f32x4 pacc[4];
#pragma unroll
    for (int ni = 0; ni < 4; ni++) {
      bf16x8 b0 = *(const bf16x8*)((const char*)KQsk + swzb(ni * 16 + fr, fq * 16));
      bf16x8 b1 = *(const bf16x8*)((const char*)KQsk + swzb(ni * 16 + fr, fq * 16 + 64));
      pacc[ni] = __builtin_amdgcn_mfma_f32_16x16x32_bf16(a0, b0, f32x4{0.f, 0.f, 0.f, 0.f}, 0, 0, 0);
      pacc[ni] = __builtin_amdgcn_mfma_f32_16x16x32_bf16(a1, b1, pacc[ni], 0, 0, 0);
    }
    float dg[4];
#pragma unroll
    for (int j = 0; j < 4; j++) dg[j] = diag[w * 16 + fq * 4 + j];
#pragma unroll
    for (int ni = 0; ni < 4; ni++)
#pragma unroll
      for (int j = 0; j < 4; j++) {
        int row = w * 16 + fq * 4 + j, col = ni * 16 + fr;
        float pv = pacc[ni][j];
        pv = (col < row) ? pv : ((col == row) ? dg[j] : 0.f);
        *(unsigned short*)((char*)Pl + swzb(row, col * 2)) = f2bfu(pv);
      }
    __syncthreads();

    // ---- phase E: O = P@V + RQ@S0 ; KV = KQ^T@V ----
    bf16x8 pA0 = *(const bf16x8*)((const char*)Pl + swzb(w * 16 + fr, fq * 16));
    bf16x8 pA1 = *(const bf16x8*)((const char*)Pl + swzb(w * 16 + fr, fq * 16 + 64));
    bf16x8 kA0 = *(const bf16x8*)((const char*)KQks + swzb(w * 16 + fr, fq * 16));
    bf16x8 kA1 = *(const bf16x8*)((const char*)KQks + swzb(w * 16 + fr, fq * 16 + 64));
    f32x4 oacc[4], kvacc[4];
#pragma unroll
    for (int ni = 0; ni < 4; ni++) {
      bf16x8 bv0 = *(const bf16x8*)((const char*)Vt + swzb(ni * 16 + fr, fq * 16));
      bf16x8 bv1 = *(const bf16x8*)((const char*)Vt + swzb(ni * 16 + fr, fq * 16 + 64));
      bf16x8 bs0 = *(const bf16x8*)((const char*)S0T + swzb(ni * 16 + fr, fq * 16));
      bf16x8 bs1 = *(const bf16x8*)((const char*)S0T + swzb(ni * 16 + fr, fq * 16 + 64));
      oacc[ni] = __builtin_amdgcn_mfma_f32_16x16x32_bf16(pA0, bv0, f32x4{0.f, 0.f, 0.f, 0.f}, 0, 0, 0);
      oacc[ni] = __builtin_amdgcn_mfma_f32_16x16x32_bf16(pA1, bv1, oacc[ni], 0, 0, 0);
      oacc[ni] = __builtin_amdgcn_mfma_f32_16x16x32_bf16(a0, bs0, oacc[ni], 0, 0, 0);
      oacc[ni] = __builtin_amdgcn_mfma_f32_16x16x32_bf16(a1, bs1, oacc[ni], 0, 0, 0);
      kvacc[ni] = __builtin_amdgcn_mfma_f32_16x16x32_bf16(kA0, bv0, f32x4{0.f, 0.f, 0.f, 0.f}, 0, 0, 0);
      kvacc[ni] = __builtin_amdgcn_mfma_f32_16x16x32_bf16(kA1, bv1, kvacc[ni], 0, 0, 0);
    }
    size_t obase = ((size_t)b * kT + ch * 64) * kC + h * 64;
#pragma unroll
    for (int ni = 0; ni < 4; ni++)
#pragma unroll
      for (int j = 0; j < 4; j++)
        o[obase + (size_t)(w * 16 + fq * 4 + j) * kC + ni * 16 + fr] = f2bfu(oacc[ni][j]);
    __syncthreads();

    // ---- phase G: S = DL*(S + KV), refresh S0T ----
    float dlj[4];
#pragma unroll
    for (int j = 0; j < 4; j++) dlj[j] = DLs[w * 16 + fq * 4 + j];
#pragma unroll
    for (int ni = 0; ni < 4; ni++)
#pragma unroll
      for (int j = 0; j < 4; j++) {
        int kk2 = w * 16 + fq * 4 + j, vv2 = ni * 16 + fr;
        float sn = (Sf[kk2][vv2] + kvacc[ni][j]) * dlj[j];
        Sf[kk2][vv2] = sn;
        *(unsigned short*)((char*)S0T + swzb(vv2, kk2 * 2)) = f2bfu(sn);
      }
    __syncthreads();
  }

  // ---- write final state ----
  {
    int k0 = tid >> 2, vs = (tid & 3) << 4;
    float* op = sOut + (size_t)bh * 4096 + (size_t)k0 * 64 + vs;
#pragma unroll
    for (int q = 0; q < 4; q++) {
      int v = vs + q * 4;
      float4 f4 = make_float4(Sf[k0][v], Sf[k0][v + 1], Sf[k0][v + 2], Sf[k0][v + 3]);
      ((float4*)op)[q] = f4;
    }
  }
}

// ---------- GroupNorm over N=64 per (b,t,h), times g, -> bf16 ----------
__global__ __launch_bounds__(256) void gn_k(
    const unsigned short* __restrict__ o, const unsigned short* __restrict__ gb,
    const float* __restrict__ gnw, const float* __restrict__ gnb,
    unsigned short* __restrict__ y) {
  int gi = blockIdx.x * 4 + (threadIdx.x >> 6);
  int j = threadIdx.x & 63;
  int bt = gi >> 5, h = gi & 31;
  size_t idx = (size_t)bt * kC + h * 64 + j;
  float val = bfu2f(o[idx]);
  float s = val, s2 = val * val;
#pragma unroll
  for (int m = 1; m < 64; m <<= 1) {
    s += __shfl_xor(s, m, 64);
    s2 += __shfl_xor(s2, m, 64);
  }
  float mu = s * 0.015625f;
  float var = s2 * 0.015625f - mu * mu;
  float rs = rsqrtf(var + 6.4e-4f);
  float on = (val - mu) * rs * gnw[h * 64 + j] + gnb[h * 64 + j];
  y[idx] = f2bfu(on * bfu2f(gb[idx]));
}

// ---------- workspace layout (peak ~433 MiB) ----------
constexpr size_t SZW     = (size_t)2048 * 2048 * 2;              // 8 MiB bf16 weight
constexpr size_t OFF_WRT = 0;
constexpr size_t OFF_WKT = 1 * SZW;
constexpr size_t OFF_WVT = 2 * SZW;
constexpr size_t OFF_WGT = 3 * SZW;
constexpr size_t OFF_WOT = 4 * SZW;
constexpr size_t OFF_W1T = 5 * SZW;                              // [160][2048] bf16
constexpr size_t OFF_W2T = OFF_W1T + (size_t)160 * 2048 * 2;     // [2048][160] bf16
constexpr size_t OFF_TD1 = OFF_W2T + (size_t)2048 * 160 * 2;     // [64][2048] bf16
constexpr size_t OFF_TD2 = OFF_TD1 + (size_t)64 * 2048 * 2;      // [2048][64] bf16
constexpr size_t OFF_T5  = OFF_TD2 + (size_t)2048 * 64 * 2;      // [M][160] bf16
constexpr size_t OFF_DT  = OFF_T5 + (size_t)kM * 160 * 2;        // [M][64] bf16 (dtmp)
constexpr size_t OFF_EDEC= OFF_DT + (size_t)kM * 64 * 2;         // [M][C] f32 edec; later xg bf16
constexpr size_t OFF_XMIX= OFF_EDEC + (size_t)kM * kC * 4;       // xxx/xw/xk/xv/xr bf16; later o bf16
constexpr size_t OFF_R   = OFF_XMIX + (size_t)kM * kC * 2;       // r bf16; later g bf16
constexpr size_t OFF_K   = OFF_R + (size_t)kM * kC * 2;          // k bf16; later y bf16
constexpr size_t OFF_V   = OFF_K + (size_t)kM * kC * 2;          // v bf16

extern "C" void kernel_launch(void* const* d_in, const int* in_sizes, int n_in,
                              void* d_out, int out_size, void* d_ws, size_t ws_size,
                              hipStream_t stream) {
  const float* x     = (const float*)d_in[0];
  const float* shift = (const float*)d_in[1];
  const float* s0    = (const float*)d_in[2];
  const float* maax  = (const float*)d_in[3];
  const float* maaw  = (const float*)d_in[4];
  const float* maak  = (const float*)d_in[5];
  const float* maav  = (const float*)d_in[6];
  const float* maar  = (const float*)d_in[7];
  const float* maag  = (const float*)d_in[8];
  const float* w1    = (const float*)d_in[9];
  const float* w2    = (const float*)d_in[10];
  const float* tdec  = (const float*)d_in[11];
  const float* tdw1  = (const float*)d_in[12];
  const float* tdw2  = (const float*)d_in[13];
  const float* faaaa = (const float*)d_in[14];
  const float* Wr    = (const float*)d_in[15];
  const float* Wk    = (const float*)d_in[16];
  const float* Wv    = (const float*)d_in[17];
  const float* Wg    = (const float*)d_in[18];
  const float* Wo    = (const float*)d_in[19];
  const float* gnw   = (const float*)d_in[20];
  const float* gnb   = (const float*)d_in[21];

  char* ws = (char*)d_ws;
  unsigned short* Wrt  = (unsigned short*)(ws + OFF_WRT);
  unsigned short* Wkt  = (unsigned short*)(ws + OFF_WKT);
  unsigned short* Wvt  = (unsigned short*)(ws + OFF_WVT);
  unsigned short* Wgt  = (unsigned short*)(ws + OFF_WGT);
  unsigned short* Wot  = (unsigned short*)(ws + OFF_WOT);
  unsigned short* w1t  = (unsigned short*)(ws + OFF_W1T);
  unsigned short* w2t  = (unsigned short*)(ws + OFF_W2T);
  unsigned short* td1t = (unsigned short*)(ws + OFF_TD1);
  unsigned short* td2t = (unsigned short*)(ws + OFF_TD2);
  unsigned short* t5   = (unsigned short*)(ws + OFF_T5);
  unsigned short* dtmp = (unsigned short*)(ws + OFF_DT);
  float*          edec = (float*)(ws + OFF_EDEC);
  unsigned short* xg   = (unsigned short*)(ws + OFF_EDEC); // after edec dead
  unsigned short* xmix = (unsigned short*)(ws + OFF_XMIX);
  unsigned short* obf  = (unsigned short*)(ws + OFF_XMIX); // after xmix dead
  unsigned short* rbb  = (unsigned short*)(ws + OFF_R);
  unsigned short* gbb  = (unsigned short*)(ws + OFF_R);    // after r dead
  unsigned short* kbb  = (unsigned short*)(ws + OFF_K);
  unsigned short* ybuf = (unsigned short*)(ws + OFF_K);    // after k dead
  unsigned short* vbb  = (unsigned short*)(ws + OFF_V);

  float* outp  = (float*)d_out;
  float* lx    = outp + (size_t)kM * kC;
  float* stOut = lx + (size_t)kB * kC;

  dim3 blk(256);

  // weight prep (transpose to [N][K] bf16)
  trans_bf16<<<dim3(32, 32), blk, 0, stream>>>(Wr, Wrt, 2048, 2048);
  trans_bf16<<<dim3(32, 32), blk, 0, stream>>>(Wk, Wkt, 2048, 2048);
  trans_bf16<<<dim3(32, 32), blk, 0, stream>>>(Wv, Wvt, 2048, 2048);
  trans_bf16<<<dim3(32, 32), blk, 0, stream>>>(Wg, Wgt, 2048, 2048);
  trans_bf16<<<dim3(32, 32), blk, 0, stream>>>(Wo, Wot, 2048, 2048);
  trans_bf16<<<dim3(3, 32), blk, 0, stream>>>(w1, w1t, 2048, 160);
  trans_bf16<<<dim3(1, 32), blk, 0, stream>>>(tdw1, td1t, 2048, 64);
  trans_bf16<<<dim3(32, 1), blk, 0, stream>>>(tdw2, td2t, 64, 2048);
  trans_bf16<<<dim3(32, 3), blk, 0, stream>>>(w2, w2t, 160, 2048);

  // token shift + maa_x mix (+ lx output)
  prep_x2<<<dim3(kM * kC / 4 / 256), blk, 0, stream>>>(x, shift, maax, xmix, lx);

  // t5 = tanh(xxx @ w1)  -> [M][160]
  gemm_k<128, 32, E_TANH><<<dim3(kM / 128, 5), blk, 0, stream>>>(xmix, w1t, t5, nullptr, kM, 160, 2048);

  dim3 mgrid(kM / 64, kC / 64);

  // decay path: xw -> dtmp = tanh(xw @ tdw1); edec = exp(-exp(dtmp @ tdw2 + time_decay))
  mixf_k<<<mgrid, blk, 0, stream>>>(t5, w2t, x, shift, maaw, xmix, 0);
  gemm_k<64, 64, E_TANH><<<dim3(kM / 64, 1), blk, 0, stream>>>(xmix, td1t, dtmp, nullptr, kM, 64, 2048);
  gemm_k<128, 128, E_DECAY><<<dim3(kM / 128, 16), blk, 0, stream>>>(dtmp, td2t, edec, tdec, kM, 2048, 64);

  // k, v, r projections (sequential reuse of xmix)
  mixf_k<<<mgrid, blk, 0, stream>>>(t5, w2t, x, shift, maak, xmix, 1);
  gemm_k<128, 128, E_BF16><<<dim3(kM / 128, 16), blk, 0, stream>>>(xmix, Wkt, kbb, nullptr, kM, 2048, 2048);
  mixf_k<<<mgrid, blk, 0, stream>>>(t5, w2t, x, shift, maav, xmix, 2);
  gemm_k<128, 128, E_BF16><<<dim3(kM / 128, 16), blk, 0, stream>>>(xmix, Wvt, vbb, nullptr, kM, 2048, 2048);
  mixf_k<<<mgrid, blk, 0, stream>>>(t5, w2t, x, shift, maar, xmix, 3);
  gemm_k<128, 128, E_BF16><<<dim3(kM / 128, 16), blk, 0, stream>>>(xmix, Wrt, rbb, nullptr, kM, 2048, 2048);

  // chunked WKV scan -> o (bf16, reuses xmix region), final state
  wkv_chunk_k<<<dim3(kB * kH), blk, 0, stream>>>(rbb, kbb, vbb, edec, faaaa, s0, obf, stOut);

  // g path (after wkv so xg reuses edec region, g reuses r region)
  mixf_k<<<mgrid, blk, 0, stream>>>(t5, w2t, x, shift, maag, xg, 4);
  gemm_k<128, 128, E_SILU><<<dim3(kM / 128, 16), blk, 0, stream>>>(xg, Wgt, gbb, nullptr, kM, 2048, 2048);

  // groupnorm * g -> bf16 (y reuses k region)
  gn_k<<<dim3(kM * kH / 4), blk, 0, stream>>>(obf, gbb, gnw, gnb, ybuf);

  // out = y @ Wo -> d_out
  gemm_k<128, 128, E_F32><<<dim3(kM / 128, 16), blk, 0, stream>>>(ybuf, Wot, outp, nullptr, kM, 2048, 2048);
}

// Round 4
// 1878.439 us; speedup vs baseline: 2.5514x; 1.1211x over previous
//
#include <hip/hip_runtime.h>
#include <hip/hip_bf16.h>
#include <stdint.h>

#define DEV __device__ __forceinline__

typedef __bf16 bf16x8 __attribute__((ext_vector_type(8)));
typedef float f32x4 __attribute__((ext_vector_type(4)));
typedef unsigned short u16x8 __attribute__((ext_vector_type(8)));

constexpr int kB = 4, kT = 4096, kC = 2048, kH = 32, kN = 64;
constexpr int kM = kB * kT; // 16384
constexpr int SEGN = 8, TSEG = kT / SEGN, CHN = TSEG / 64; // 8 segments x 512 t x 8 chunks

// ---------- bf16 helpers (raw ushort storage everywhere) ----------
DEV float bfu2f(unsigned short u) {
  union { uint32_t i; float f; } x; x.i = ((uint32_t)u) << 16; return x.f;
}
DEV unsigned short f2bfu(float f) {
  union { float f; uint32_t i; } x; x.f = f;
  uint32_t r = x.i + 0x7FFFu + ((x.i >> 16) & 1u);
  return (unsigned short)(r >> 16);
}

// ---------- async global->LDS (16B per lane, wave-uniform LDS base) ----------
DEV void gld16(const void* g, void* l) {
  __builtin_amdgcn_global_load_lds(
      (const __attribute__((address_space(1))) void*)g,
      (__attribute__((address_space(3))) void*)l, 16, 0, 0);
}

// ---------- generic transpose + fp32->bf16:  out[c][r] = bf16(in[r][c]) ----------
__global__ __launch_bounds__(256) void trans_bf16(
    const float* __restrict__ in, unsigned short* __restrict__ out, int R, int Cn) {
  __shared__ __attribute__((aligned(16))) unsigned short tile[64][65];
  const int t = threadIdx.x;
  const int r0 = blockIdx.y * 64, c0 = blockIdx.x * 64;
  const int lr = t >> 6, lc = t & 63;
#pragma unroll
  for (int i = 0; i < 16; i++) {
    int rr = lr + i * 4;
    int gr = r0 + rr, gc = c0 + lc;
    if (gr < R && gc < Cn) tile[rr][lc] = f2bfu(in[(size_t)gr * Cn + gc]);
  }
  __syncthreads();
#pragma unroll
  for (int i = 0; i < 16; i++) {
    int cc = lr + i * 4;
    int gc = c0 + cc, gr = r0 + lc;
    if (gc < Cn && gr < R) out[(size_t)gc * R + gr] = tile[lc][cc];
  }
}

// ---------- prep: xxx = bf16(x + (shift(x)-x)*maa_x), lx copy ----------
__global__ __launch_bounds__(256) void prep_x2(
    const float* __restrict__ x, const float* __restrict__ shift,
    const float* __restrict__ maax,
    unsigned short* __restrict__ xxx, float* __restrict__ lx) {
  size_t i4 = ((size_t)blockIdx.x * 256 + threadIdx.x) * 4;
  int c = (int)(i4 & (kC - 1));
  size_t bt = i4 >> 11;           // /C
  int tt = (int)(bt & (kT - 1));
  int b = (int)(bt >> 12);        // /T
  float4 xv = *(const float4*)(x + i4);
  float4 pv = (tt == 0) ? *(const float4*)(shift + (size_t)b * kC + c)
                        : *(const float4*)(x + i4 - kC);
  float4 mx = *(const float4*)(maax + c);
  ushort4 o4;
  o4.x = f2bfu(xv.x + (pv.x - xv.x) * mx.x);
  o4.y = f2bfu(xv.y + (pv.y - xv.y) * mx.y);
  o4.z = f2bfu(xv.z + (pv.z - xv.z) * mx.z);
  o4.w = f2bfu(xv.w + (pv.w - xv.w) * mx.w);
  *(ushort4*)(xxx + i4) = o4;
  if (tt == kT - 1) *(float4*)(lx + (size_t)b * kC + c) = xv;
}

// ---------- bf16 MFMA GEMM:  C[M][N] = A[M][K] * Bt[N][K]^T, fp32 acc ----------
enum { E_F32 = 0, E_BF16 = 1, E_TANH = 2, E_SILU = 3, E_DECAY = 4 };

template <int BM, int BN, int EPI>
__global__ __launch_bounds__(256) void gemm_k(
    const unsigned short* __restrict__ A, const unsigned short* __restrict__ Bt,
    void* __restrict__ Cout, const float* __restrict__ aux, int M, int N, int K) {
  constexpr int WGM = (BM == 128 && BN == 128) ? 2 : (BM == 64 ? 2 : 4);
  constexpr int WGN = 4 / WGM;
  constexpr int WM = BM / WGM, WN = BN / WGN;
  constexpr int WR = WM / 16, WC = WN / 16;
  __shared__ __attribute__((aligned(16))) unsigned short As[BM * 32];
  __shared__ __attribute__((aligned(16))) unsigned short Bs[BN * 32];
  const int t = threadIdx.x, wid = t >> 6, l = t & 63;
  const int m0 = blockIdx.x * BM, n0 = blockIdx.y * BN;
  const int wm0 = (wid / WGN) * WM, wn0 = (wid % WGN) * WN;
  f32x4 acc[WR][WC];
#pragma unroll
  for (int i = 0; i < WR; i++)
#pragma unroll
    for (int j = 0; j < WC; j++) acc[i][j] = f32x4{0.f, 0.f, 0.f, 0.f};

  const int rowS = t >> 2, cbS = (t & 3) * 16;
  const char* Ab = (const char*)A;
  const char* Bb = (const char*)Bt;
  const int aoff = (wm0 + (l & 15)) * 32 + (l >> 4) * 8;
  const int boff = (wn0 + (l & 15)) * 32 + (l >> 4) * 8;

  for (int kt = 0; kt < K; kt += 32) {
#pragma unroll
    for (int ia = 0; ia < BM / 64; ia++)
      gld16(Ab + ((size_t)(m0 + ia * 64 + rowS) * K + kt) * 2 + cbS,
            (char*)As + ia * 4096 + wid * 1024);
    if constexpr (BN >= 64) {
#pragma unroll
      for (int ib = 0; ib < BN / 64; ib++)
        gld16(Bb + ((size_t)(n0 + ib * 64 + rowS) * K + kt) * 2 + cbS,
              (char*)Bs + ib * 4096 + wid * 1024);
    } else {
      if (t < BN * 4)
        gld16(Bb + ((size_t)(n0 + rowS) * K + kt) * 2 + cbS,
              (char*)Bs + wid * 1024);
    }
    __syncthreads();
    bf16x8 af[WR], bfv[WC];
#pragma unroll
    for (int mi = 0; mi < WR; mi++) af[mi] = *(const bf16x8*)(&As[aoff + mi * 512]);
#pragma unroll
    for (int ni = 0; ni < WC; ni++) bfv[ni] = *(const bf16x8*)(&Bs[boff + ni * 512]);
#pragma unroll
    for (int mi = 0; mi < WR; mi++)
#pragma unroll
      for (int ni = 0; ni < WC; ni++)
        acc[mi][ni] = __builtin_amdgcn_mfma_f32_16x16x32_bf16(af[mi], bfv[ni], acc[mi][ni], 0, 0, 0);
    __syncthreads();
  }

#pragma unroll
  for (int mi = 0; mi < WR; mi++) {
#pragma unroll
    for (int ni = 0; ni < WC; ni++) {
      int row = m0 + wm0 + mi * 16 + (l >> 4) * 4;
      int col = n0 + wn0 + ni * 16 + (l & 15);
#pragma unroll
      for (int j = 0; j < 4; j++) {
        float v = acc[mi][ni][j];
        size_t idx = (size_t)(row + j) * N + col;
        if constexpr (EPI == E_F32) ((float*)Cout)[idx] = v;
        else if constexpr (EPI == E_BF16) ((unsigned short*)Cout)[idx] = f2bfu(v);
        else if constexpr (EPI == E_TANH) ((unsigned short*)Cout)[idx] = f2bfu(tanhf(v));
        else if constexpr (EPI == E_SILU) ((unsigned short*)Cout)[idx] = f2bfu(v / (1.f + expf(-v)));
        else if constexpr (EPI == E_DECAY) {
          float w = v + aux[col];
          ((float*)Cout)[idx] = expf(-expf(w));
        }
      }
    }
  }
}

// ---------- single-feature mix:  m = t5[:,f*32:(f+1)*32] @ w2t[:,f*32:(f+1)*32]^T
//            xout = bf16( x + (shift(x)-x) * (maa + m) )
__global__ __launch_bounds__(256) void mixf_k(
    const unsigned short* __restrict__ t5, const unsigned short* __restrict__ w2t,
    const float* __restrict__ x, const float* __restrict__ shift,
    const float* __restrict__ maa, unsigned short* __restrict__ xout, int f) {
  __shared__ __attribute__((aligned(16))) unsigned short As[64 * 32];
  __shared__ __attribute__((aligned(16))) unsigned short Bs[64 * 32];
  const int t = threadIdx.x, wid = t >> 6, l = t & 63;
  const int m0 = blockIdx.x * 64, n0 = blockIdx.y * 64;
  const int wm0 = (wid >> 1) * 32, wn0 = (wid & 1) * 32;
  const int rowS = t >> 2, cbS = (t & 3) * 16;
  const int aoff = (wm0 + (l & 15)) * 32 + (l >> 4) * 8;
  const int boff = (wn0 + (l & 15)) * 32 + (l >> 4) * 8;

  gld16((const char*)t5 + ((size_t)(m0 + rowS) * 160 + f * 32) * 2 + cbS, (char*)As + wid * 1024);
  gld16((const char*)w2t + ((size_t)(n0 + rowS) * 160 + f * 32) * 2 + cbS, (char*)Bs + wid * 1024);
  __syncthreads();
  bf16x8 a0 = *(const bf16x8*)(&As[aoff]), a1 = *(const bf16x8*)(&As[aoff + 512]);
  bf16x8 b0 = *(const bf16x8*)(&Bs[boff]), b1 = *(const bf16x8*)(&Bs[boff + 512]);
  f32x4 acc[2][2];
  acc[0][0] = f32x4{0.f, 0.f, 0.f, 0.f}; acc[0][1] = f32x4{0.f, 0.f, 0.f, 0.f};
  acc[1][0] = f32x4{0.f, 0.f, 0.f, 0.f}; acc[1][1] = f32x4{0.f, 0.f, 0.f, 0.f};
  acc[0][0] = __builtin_amdgcn_mfma_f32_16x16x32_bf16(a0, b0, acc[0][0], 0, 0, 0);
  acc[0][1] = __builtin_amdgcn_mfma_f32_16x16x32_bf16(a0, b1, acc[0][1], 0, 0, 0);
  acc[1][0] = __builtin_amdgcn_mfma_f32_16x16x32_bf16(a1, b0, acc[1][0], 0, 0, 0);
  acc[1][1] = __builtin_amdgcn_mfma_f32_16x16x32_bf16(a1, b1, acc[1][1], 0, 0, 0);

#pragma unroll
  for (int mi = 0; mi < 2; mi++)
#pragma unroll
    for (int ni = 0; ni < 2; ni++) {
      int row = m0 + wm0 + mi * 16 + (l >> 4) * 4;
      int col = n0 + wn0 + ni * 16 + (l & 15);
      float mv = maa[col];
#pragma unroll
      for (int j = 0; j < 4; j++) {
        int rrow = row + j;
        int tt = rrow & (kT - 1);
        size_t idx = (size_t)rrow * kC + col;
        float xv = x[idx];
        float pv = (tt == 0) ? shift[(size_t)(rrow >> 12) * kC + col] : x[idx - kC];
        xout[idx] = f2bfu(xv + (pv - xv) * (mv + acc[mi][ni][j]));
      }
    }
}

// swizzled byte offset within a [64-row][128B] bf16 LDS tile
DEV int swzb(int row, int byteoff) { return (row << 7) + (byteoff ^ ((row & 7) << 4)); }

// ---------- WKV pass 1: per-segment local state (zero init) + decay product ----------
__global__ __launch_bounds__(256) void wkv_local_k(
    const unsigned short* __restrict__ kb, const unsigned short* __restrict__ vb,
    const float* __restrict__ ed, float* __restrict__ Lbuf, float* __restrict__ Dseg) {
  const int bid = blockIdx.x;            // bh*SEGN + seg
  const int bh = bid >> 3, seg = bid & 7;
  const int h = bh & 31, b = bh >> 5;
  const int tid = threadIdx.x, w = tid >> 6, l = tid & 63;
  __shared__ __attribute__((aligned(16))) unsigned short KQks[4096]; // [k][s] swz
  __shared__ __attribute__((aligned(16))) unsigned short Vt[4096];   // [v][s] swz
  __shared__ __attribute__((aligned(16))) float Sf[64][68];
  __shared__ float segp[4][64];
  __shared__ float DLs[64];

  const int fr = l & 15, fq = l >> 4;
  // zero the state cells this thread owns (same mapping as update phase)
#pragma unroll
  for (int ni = 0; ni < 4; ni++)
#pragma unroll
    for (int j = 0; j < 4; j++) Sf[w * 16 + fq * 4 + j][ni * 16 + fr] = 0.f;

  float dtot = 1.f;
  float kv[16], dv[16], vv[16];
  {
    size_t g = ((size_t)b * kT + seg * TSEG + w * 16) * kC + h * 64 + l;
#pragma unroll
    for (int i = 0; i < 16; i++) {
      kv[i] = bfu2f(kb[g]); vv[i] = bfu2f(vb[g]); dv[i] = ed[g];
      g += kC;
    }
  }

  for (int ch = 0; ch < CHN; ++ch) {
    float p = 1.f;
#pragma unroll
    for (int i = 0; i < 16; i++) p *= dv[i];
    segp[w][l] = p;
    __syncthreads();
    float pre = 1.f;
    if (w > 0) pre *= segp[0][l];
    if (w > 1) pre *= segp[1][l];
    if (w > 2) pre *= segp[2][l];
    if (w == 3) DLs[l] = pre * p;

    unsigned short kqrow[16], vtrow[16];
    float run = pre;
#pragma unroll
    for (int i = 0; i < 16; i++) {
      run *= dv[i];
      kqrow[i] = f2bfu(kv[i] / run);
      vtrow[i] = f2bfu(vv[i]);
    }
    {
      u16x8 q0, q1, v0, v1;
#pragma unroll
      for (int j = 0; j < 8; j++) { q0[j] = kqrow[j]; q1[j] = kqrow[j + 8]; v0[j] = vtrow[j]; v1[j] = vtrow[j + 8]; }
      *(u16x8*)((char*)KQks + swzb(l, w * 32)) = q0;
      *(u16x8*)((char*)KQks + swzb(l, w * 32 + 16)) = q1;
      *(u16x8*)((char*)Vt + swzb(l, w * 32)) = v0;
      *(u16x8*)((char*)Vt + swzb(l, w * 32 + 16)) = v1;
    }
    if (ch < CHN - 1) {
      size_t g = ((size_t)b * kT + seg * TSEG + (ch + 1) * 64 + w * 16) * kC + h * 64 + l;
#pragma unroll
      for (int i = 0; i < 16; i++) {
        kv[i] = bfu2f(kb[g]); vv[i] = bfu2f(vb[g]); dv[i] = ed[g];
        g += kC;
      }
    }
    __syncthreads();

    bf16x8 kA0 = *(const bf16x8*)((const char*)KQks + swzb(w * 16 + fr, fq * 16));
    bf16x8 kA1 = *(const bf16x8*)((const char*)KQks + swzb(w * 16 + fr, fq * 16 + 64));
    f32x4 kvacc[4];
#pragma unroll
    for (int ni = 0; ni < 4; ni++) {
      bf16x8 bv0 = *(const bf16x8*)((const char*)Vt + swzb(ni * 16 + fr, fq * 16));
      bf16x8 bv1 = *(const bf16x8*)((const char*)Vt + swzb(ni * 16 + fr, fq * 16 + 64));
      kvacc[ni] = __builtin_amdgcn_mfma_f32_16x16x32_bf16(kA0, bv0, f32x4{0.f, 0.f, 0.f, 0.f}, 0, 0, 0);
      kvacc[ni] = __builtin_amdgcn_mfma_f32_16x16x32_bf16(kA1, bv1, kvacc[ni], 0, 0, 0);
    }
    float dlj[4];
#pragma unroll
    for (int j = 0; j < 4; j++) dlj[j] = DLs[w * 16 + fq * 4 + j];
#pragma unroll
    for (int ni = 0; ni < 4; ni++)
#pragma unroll
      for (int j = 0; j < 4; j++) {
        int kk2 = w * 16 + fq * 4 + j, vv2 = ni * 16 + fr;
        Sf[kk2][vv2] = (Sf[kk2][vv2] + kvacc[ni][j]) * dlj[j];
      }
    dtot *= DLs[l];
    __syncthreads();
  }

  float* Lp = Lbuf + (size_t)bid * 4096;
#pragma unroll
  for (int ni = 0; ni < 4; ni++)
#pragma unroll
    for (int j = 0; j < 4; j++)
      Lp[(size_t)(w * 16 + fq * 4 + j) * 64 + ni * 16 + fr] = Sf[w * 16 + fq * 4 + j][ni * 16 + fr];
  if (w == 0) Dseg[(size_t)bid * 64 + l] = dtot;
}

// ---------- WKV combine: Sini[i] = scan of (Dseg, L); in-place L -> Sini; final -> sOut ----------
__global__ __launch_bounds__(256) void wkv_combine_k(
    const float* __restrict__ s0, const float* __restrict__ Dseg,
    float* __restrict__ Lbuf, float* __restrict__ sOut) {
  const int bh = blockIdx.x, tid = threadIdx.x;
  const int k = tid >> 2, v0 = (tid & 3) * 16;
  float4 s[4];
  const float* sp = s0 + (size_t)bh * 4096 + (size_t)k * 64 + v0;
#pragma unroll
  for (int q = 0; q < 4; q++) s[q] = ((const float4*)sp)[q];
  for (int seg = 0; seg < SEGN; ++seg) {
    size_t idx = (size_t)bh * SEGN + seg;
    float d = Dseg[idx * 64 + k];
    float* Lp = Lbuf + idx * 4096 + (size_t)k * 64 + v0;
#pragma unroll
    for (int q = 0; q < 4; q++) {
      float4 lq = ((float4*)Lp)[q];
      ((float4*)Lp)[q] = s[q];
      s[q].x = d * s[q].x + lq.x; s[q].y = d * s[q].y + lq.y;
      s[q].z = d * s[q].z + lq.z; s[q].w = d * s[q].w + lq.w;
    }
  }
  float* op = sOut + (size_t)bh * 4096 + (size_t)k * 64 + v0;
#pragma unroll
  for (int q = 0; q < 4; q++) ((float4*)op)[q] = s[q];
}

// ---------- WKV pass 2: per-segment full output pipeline (init from Sini) ----------
__global__ __launch_bounds__(256) void wkv_seg_k(
    const unsigned short* __restrict__ rb, const unsigned short* __restrict__ kb,
    const unsigned short* __restrict__ vb, const float* __restrict__ ed,
    const float* __restrict__ uf, const float* __restrict__ Sini,
    unsigned short* __restrict__ o) {
  const int bid = blockIdx.x;            // bh*SEGN + seg
  const int bh = bid >> 3, seg = bid & 7;
  const int h = bh & 31, b = bh >> 5;
  const int tid = threadIdx.x, w = tid >> 6, l = tid & 63;
  __shared__ __attribute__((aligned(16))) unsigned short RQ[4096];   // [t][k] swz bf16
  __shared__ __attribute__((aligned(16))) unsigned short KQsk[4096]; // [s][k] swz
  __shared__ __attribute__((aligned(16))) unsigned short KQks[4096]; // [k][s] swz
  __shared__ __attribute__((aligned(16))) unsigned short Vt[4096];   // [v][s] swz
  __shared__ __attribute__((aligned(16))) unsigned short Pl[4096];   // [t][s] swz
  __shared__ __attribute__((aligned(16))) unsigned short S0T[4096];  // [v][k] swz
  __shared__ __attribute__((aligned(16))) float Sf[64][68];          // fp32 master state
  __shared__ float segp[4][64];
  __shared__ float DLs[64];
  __shared__ float diag[64];

  const float uu = uf[h * 64 + l];

  // ---- init state from Sini: fp32 master + bf16 transposed copy ----
  {
    int k0 = tid >> 2, vs = (tid & 3) << 4;
    const float* sp = Sini + (size_t)bid * 4096 + (size_t)k0 * 64 + vs;
#pragma unroll
    for (int q = 0; q < 4; q++) {
      float4 f4 = ((const float4*)sp)[q];
      int v = vs + q * 4;
      Sf[k0][v + 0] = f4.x; Sf[k0][v + 1] = f4.y; Sf[k0][v + 2] = f4.z; Sf[k0][v + 3] = f4.w;
      *(unsigned short*)((char*)S0T + swzb(v + 0, k0 * 2)) = f2bfu(f4.x);
      *(unsigned short*)((char*)S0T + swzb(v + 1, k0 * 2)) = f2bfu(f4.y);
      *(unsigned short*)((char*)S0T + swzb(v + 2, k0 * 2)) = f2bfu(f4.z);
      *(unsigned short*)((char*)S0T + swzb(v + 3, k0 * 2)) = f2bfu(f4.w);
    }
  }
  __syncthreads();

  const int fr = l & 15, fq = l >> 4;
  float rv[16], kv[16], dv[16], vv[16];

  {
    size_t g = ((size_t)b * kT + seg * TSEG + w * 16) * kC + h * 64 + l;
#pragma unroll
    for (int i = 0; i < 16; i++) {
      rv[i] = bfu2f(rb[g]); kv[i] = bfu2f(kb[g]); vv[i] = bfu2f(vb[g]); dv[i] = ed[g];
      g += kC;
    }
  }

  for (int ch = 0; ch < CHN; ++ch) {
    // ---- phase A: cumprods, RQ/KQ/Vt tiles, diag ----
    float p = 1.f;
#pragma unroll
    for (int i = 0; i < 16; i++) p *= dv[i];
    segp[w][l] = p;
    __syncthreads();
    float pre = 1.f;
    if (w > 0) pre *= segp[0][l];
    if (w > 1) pre *= segp[1][l];
    if (w > 2) pre *= segp[2][l];
    if (w == 3) DLs[l] = pre * p;

    unsigned short kqrow[16], vtrow[16];
    float run = pre;
#pragma unroll
    for (int i = 0; i < 16; i++) {
      int t = w * 16 + i;
      float rq = rv[i] * run;
      run *= dv[i];
      float kq = kv[i] / run;
      *(unsigned short*)((char*)RQ + swzb(t, l * 2)) = f2bfu(rq);
      unsigned short kqu = f2bfu(kq);
      *(unsigned short*)((char*)KQsk + swzb(t, l * 2)) = kqu;
      kqrow[i] = kqu;
      vtrow[i] = f2bfu(vv[i]);
    }
    {
      u16x8 q0, q1, v0, v1;
#pragma unroll
      for (int j = 0; j < 8; j++) { q0[j] = kqrow[j]; q1[j] = kqrow[j + 8]; v0[j] = vtrow[j]; v1[j] = vtrow[j + 8]; }
      *(u16x8*)((char*)KQks + swzb(l, w * 32)) = q0;
      *(u16x8*)((char*)KQks + swzb(l, w * 32 + 16)) = q1;
      *(u16x8*)((char*)Vt + swzb(l, w * 32)) = v0;
      *(u16x8*)((char*)Vt + swzb(l, w * 32 + 16)) = v1;
    }
#pragma unroll
    for (int i = 0; i < 16; i++) {
      float dsv = rv[i] * uu * kv[i];
#pragma unroll
      for (int m = 1; m < 64; m <<= 1) dsv += __shfl_xor(dsv, m, 64);
      if (l == 0) diag[w * 16 + i] = dsv;
    }

    // ---- issue next chunk's loads (latency hides under MFMA phases) ----
    if (ch < CHN - 1) {
      size_t g = ((size_t)b * kT + seg * TSEG + (ch + 1) * 64 + w * 16) * kC + h * 64 + l;
#pragma unroll
      for (int i = 0; i < 16; i++) {
        rv[i] = bfu2f(rb[g]); kv[i] = bfu2f(kb[g]); vv[i] = bfu2f(vb[g]); dv[i] = ed[g];
        g += kC;
      }
    }
    __syncthreads();

    // ---- phase C: P = strict_lower(RQ @ KQ^T) + u-diag ----
    bf16x8 a0 = *(const bf16x8*)((const char*)RQ + swzb(w * 16 + fr, fq * 16));
    bf16x8 a1 = *(const bf16x8*)((const char*)RQ + swzb(w * 16 + fr, fq * 16 + 64));
    f32x4 pacc[4];
#pragma unroll
    for (int ni = 0; ni < 4; ni++) {
      bf16x8 b0 = *(const bf16x8*)((const char*)KQsk + swzb(ni * 16 + fr, fq * 16));
      bf16x8 b1 = *(const bf16x8*)((const char*)KQsk + swzb(ni * 16 + fr, fq * 16 + 64));
      pacc[ni] = __builtin_amdgcn_mfma_f32_16x16x32_bf16(a0, b0, f32x4{0.f, 0.f, 0.f, 0.f}, 0, 0, 0);
      pacc[ni] = __builtin_amdgcn_mfma_f32_16x16x32_bf16(a1, b1, pacc[ni], 0, 0, 0);
    }
    float dg[4];
#pragma unroll
    for (int j = 0; j < 4; j++) dg[j] = diag[w * 16 + fq * 4 + j];
#pragma unroll
    for (int ni = 0; ni < 4; ni++)
#pragma unroll
      for (int j = 0; j < 4; j++) {
        int row = w * 16 + fq * 4 + j, col = ni * 16 + fr;
        float pv = pacc[ni][j];
        pv = (col < row) ? pv : ((col == row) ? dg[j] : 0.f);
        *(unsigned short*)((char*)Pl + swzb(row, col * 2)) = f2bfu(pv);
      }
    __syncthreads();

    // ---- phase E: O = P@V + RQ@S0 ; KV = KQ^T@V ----
    bf16x8 pA0 = *(const bf16x8*)((const char*)Pl + swzb(w * 16 + fr, fq * 16));
    bf16x8 pA1 = *(const bf16x8*)((const char*)Pl + swzb(w * 16 + fr, fq * 16 + 64));
    bf16x8 kA0 = *(const bf16x8*)((const char*)KQks + swzb(w * 16 + fr, fq * 16));
    bf16x8 kA1 = *(const bf16x8*)((const char*)KQks + swzb(w * 16 + fr, fq * 16 + 64));
    f32x4 oacc[4], kvacc[4];
#pragma unroll
    for (int ni = 0; ni < 4; ni++) {
      bf16x8 bv0 = *(const bf16x8*)((const char*)Vt + swzb(ni * 16 + fr, fq * 16));
      bf16x8 bv1 = *(const bf16x8*)((const char*)Vt + swzb(ni * 16 + fr, fq * 16 + 64));
      bf16x8 bs0 = *(const bf16x8*)((const char*)S0T + swzb(ni * 16 + fr, fq * 16));
      bf16x8 bs1 = *(const bf16x8*)((const char*)S0T + swzb(ni * 16 + fr, fq * 16 + 64));
      oacc[ni] = __builtin_amdgcn_mfma_f32_16x16x32_bf16(pA0, bv0, f32x4{0.f, 0.f, 0.f, 0.f}, 0, 0, 0);
      oacc[ni] = __builtin_amdgcn_mfma_f32_16x16x32_bf16(pA1, bv1, oacc[ni], 0, 0, 0);
      oacc[ni] = __builtin_amdgcn_mfma_f32_16x16x32_bf16(a0, bs0, oacc[ni], 0, 0, 0);
      oacc[ni] = __builtin_amdgcn_mfma_f32_16x16x32_bf16(a1, bs1, oacc[ni], 0, 0, 0);
      kvacc[ni] = __builtin_amdgcn_mfma_f32_16x16x32_bf16(kA0, bv0, f32x4{0.f, 0.f, 0.f, 0.f}, 0, 0, 0);
      kvacc[ni] = __builtin_amdgcn_mfma_f32_16x16x32_bf16(kA1, bv1, kvacc[ni], 0, 0, 0);
    }
    size_t obase = ((size_t)b * kT + seg * TSEG + ch * 64) * kC + h * 64;
#pragma unroll
    for (int ni = 0; ni < 4; ni++)
#pragma unroll
      for (int j = 0; j < 4; j++)
        o[obase + (size_t)(w * 16 + fq * 4 + j) * kC + ni * 16 + fr] = f2bfu(oacc[ni][j]);
    __syncthreads();

    // ---- phase G: S = DL*(S + KV), refresh S0T ----
    float dlj[4];
#pragma unroll
    for (int j = 0; j < 4; j++) dlj[j] = DLs[w * 16 + fq * 4 + j];
#pragma unroll
    for (int ni = 0; ni < 4; ni++)
#pragma unroll
      for (int j = 0; j < 4; j++) {
        int kk2 = w * 16 + fq * 4 + j, vv2 = ni * 16 + fr;
        float sn = (Sf[kk2][vv2] + kvacc[ni][j]) * dlj[j];
        Sf[kk2][vv2] = sn;
        *(unsigned short*)((char*)S0T + swzb(vv2, kk2 * 2)) = f2bfu(sn);
      }
    __syncthreads();
  }
}

// ---------- GroupNorm over N=64 per (b,t,h), times g, -> bf16 ----------
__global__ __launch_bounds__(256) void gn_k(
    const unsigned short* __restrict__ o, const unsigned short* __restrict__ gb,
    const float* __restrict__ gnw, const float* __restrict__ gnb,
    unsigned short* __restrict__ y) {
  int gi = blockIdx.x * 4 + (threadIdx.x >> 6);
  int j = threadIdx.x & 63;
  int bt = gi >> 5, h = gi & 31;
  size_t idx = (size_t)bt * kC + h * 64 + j;
  float val = bfu2f(o[idx]);
  float s = val, s2 = val * val;
#pragma unroll
  for (int m = 1; m < 64; m <<= 1) {
    s += __shfl_xor(s, m, 64);
    s2 += __shfl_xor(s2, m, 64);
  }
  float mu = s * 0.015625f;
  float var = s2 * 0.015625f - mu * mu;
  float rs = rsqrtf(var + 6.4e-4f);
  float on = (val - mu) * rs * gnw[h * 64 + j] + gnb[h * 64 + j];
  y[idx] = f2bfu(on * bfu2f(gb[idx]));
}

// ---------- workspace layout (peak ~433 MiB) ----------
constexpr size_t SZW     = (size_t)2048 * 2048 * 2;              // 8 MiB bf16 weight
constexpr size_t OFF_WRT = 0;
constexpr size_t OFF_WKT = 1 * SZW;
constexpr size_t OFF_WVT = 2 * SZW;
constexpr size_t OFF_WGT = 3 * SZW;
constexpr size_t OFF_WOT = 4 * SZW;
constexpr size_t OFF_W1T = 5 * SZW;                              // [160][2048] bf16
constexpr size_t OFF_W2T = OFF_W1T + (size_t)160 * 2048 * 2;     // [2048][160] bf16
constexpr size_t OFF_TD1 = OFF_W2T + (size_t)2048 * 160 * 2;     // [64][2048] bf16; later Dseg f32
constexpr size_t OFF_TD2 = OFF_TD1 + (size_t)64 * 2048 * 2;      // [2048][64] bf16
constexpr size_t OFF_T5  = OFF_TD2 + (size_t)2048 * 64 * 2;      // [M][160] bf16
constexpr size_t OFF_DT  = OFF_T5 + (size_t)kM * 160 * 2;        // [M][64] bf16 (dtmp)
constexpr size_t OFF_EDEC= OFF_DT + (size_t)kM * 64 * 2;         // [M][C] f32 edec; later xg bf16
constexpr size_t OFF_XMIX= OFF_EDEC + (size_t)kM * kC * 4;       // xxx/xw/xk/xv/xr bf16; later o bf16
constexpr size_t OFF_R   = OFF_XMIX + (size_t)kM * kC * 2;       // r bf16; later g bf16
constexpr size_t OFF_K   = OFF_R + (size_t)kM * kC * 2;          // k bf16; later y bf16
constexpr size_t OFF_V   = OFF_K + (size_t)kM * kC * 2;          // v bf16
// L/Sini (16.78 MiB) reuses OFF_WRT..OFF_WVT (Wr^T,Wk^T dead after r/k GEMMs)
constexpr size_t OFF_L   = OFF_WRT;

extern "C" void kernel_launch(void* const* d_in, const int* in_sizes, int n_in,
                              void* d_out, int out_size, void* d_ws, size_t ws_size,
                              hipStream_t stream) {
  const float* x     = (const float*)d_in[0];
  const float* shift = (const float*)d_in[1];
  const float* s0    = (const float*)d_in[2];
  const float* maax  = (const float*)d_in[3];
  const float* maaw  = (const float*)d_in[4];
  const float* maak  = (const float*)d_in[5];
  const float* maav  = (const float*)d_in[6];
  const float* maar  = (const float*)d_in[7];
  const float* maag  = (const float*)d_in[8];
  const float* w1    = (const float*)d_in[9];
  const float* w2    = (const float*)d_in[10];
  const float* tdec  = (const float*)d_in[11];
  const float* tdw1  = (const float*)d_in[12];
  const float* tdw2  = (const float*)d_in[13];
  const float* faaaa = (const float*)d_in[14];
  const float* Wr    = (const float*)d_in[15];
  const float* Wk    = (const float*)d_in[16];
  const float* Wv    = (const float*)d_in[17];
  const float* Wg    = (const float*)d_in[18];
  const float* Wo    = (const float*)d_in[19];
  const float* gnw   = (const float*)d_in[20];
  const float* gnb   = (const float*)d_in[21];

  char* ws = (char*)d_ws;
  unsigned short* Wrt  = (unsigned short*)(ws + OFF_WRT);
  unsigned short* Wkt  = (unsigned short*)(ws + OFF_WKT);
  unsigned short* Wvt  = (unsigned short*)(ws + OFF_WVT);
  unsigned short* Wgt  = (unsigned short*)(ws + OFF_WGT);
  unsigned short* Wot  = (unsigned short*)(ws + OFF_WOT);
  unsigned short* w1t  = (unsigned short*)(ws + OFF_W1T);
  unsigned short* w2t  = (unsigned short*)(ws + OFF_W2T);
  unsigned short* td1t = (unsigned short*)(ws + OFF_TD1);
  unsigned short* td2t = (unsigned short*)(ws + OFF_TD2);
  unsigned short* t5   = (unsigned short*)(ws + OFF_T5);
  unsigned short* dtmp = (unsigned short*)(ws + OFF_DT);
  float*          edec = (float*)(ws + OFF_EDEC);
  unsigned short* xg   = (unsigned short*)(ws + OFF_EDEC); // after edec dead
  unsigned short* xmix = (unsigned short*)(ws + OFF_XMIX);
  unsigned short* obf  = (unsigned short*)(ws + OFF_XMIX); // after xmix dead
  unsigned short* rbb  = (unsigned short*)(ws + OFF_R);
  unsigned short* gbb  = (unsigned short*)(ws + OFF_R);    // after r dead
  unsigned short* kbb  = (unsigned short*)(ws + OFF_K);
  unsigned short* ybuf = (unsigned short*)(ws + OFF_K);    // after k dead
  unsigned short* vbb  = (unsigned short*)(ws + OFF_V);
  float*          Lbuf = (float*)(ws + OFF_L);             // after Wrt/Wkt dead
  float*          DsegP= (float*)(ws + OFF_TD1);           // after td1t dead

  float* outp  = (float*)d_out;
  float* lx    = outp + (size_t)kM * kC;
  float* stOut = lx + (size_t)kB * kC;

  dim3 blk(256);

  // weight prep (transpose to [N][K] bf16)
  trans_bf16<<<dim3(32, 32), blk, 0, stream>>>(Wr, Wrt, 2048, 2048);
  trans_bf16<<<dim3(32, 32), blk, 0, stream>>>(Wk, Wkt, 2048, 2048);
  trans_bf16<<<dim3(32, 32), blk, 0, stream>>>(Wv, Wvt, 2048, 2048);
  trans_bf16<<<dim3(32, 32), blk, 0, stream>>>(Wg, Wgt, 2048, 2048);
  trans_bf16<<<dim3(32, 32), blk, 0, stream>>>(Wo, Wot, 2048, 2048);
  trans_bf16<<<dim3(3, 32), blk, 0, stream>>>(w1, w1t, 2048, 160);
  trans_bf16<<<dim3(1, 32), blk, 0, stream>>>(tdw1, td1t, 2048, 64);
  trans_bf16<<<dim3(32, 1), blk, 0, stream>>>(tdw2, td2t, 64, 2048);
  trans_bf16<<<dim3(32, 3), blk, 0, stream>>>(w2, w2t, 160, 2048);

  // token shift + maa_x mix (+ lx output)
  prep_x2<<<dim3(kM * kC / 4 / 256), blk, 0, stream>>>(x, shift, maax, xmix, lx);

  // t5 = tanh(xxx @ w1)  -> [M][160]
  gemm_k<128, 32, E_TANH><<<dim3(kM / 128, 5), blk, 0, stream>>>(xmix, w1t, t5, nullptr, kM, 160, 2048);

  dim3 mgrid(kM / 64, kC / 64);

  // decay path: xw -> dtmp = tanh(xw @ tdw1); edec = exp(-exp(dtmp @ tdw2 + time_decay))
  mixf_k<<<mgrid, blk, 0, stream>>>(t5, w2t, x, shift, maaw, xmix, 0);
  gemm_k<64, 64, E_TANH><<<dim3(kM / 64, 1), blk, 0, stream>>>(xmix, td1t, dtmp, nullptr, kM, 64, 2048);
  gemm_k<128, 128, E_DECAY><<<dim3(kM / 128, 16), blk, 0, stream>>>(dtmp, td2t, edec, tdec, kM, 2048, 64);

  // k, v, r projections (sequential reuse of xmix)
  mixf_k<<<mgrid, blk, 0, stream>>>(t5, w2t, x, shift, maak, xmix, 1);
  gemm_k<128, 128, E_BF16><<<dim3(kM / 128, 16), blk, 0, stream>>>(xmix, Wkt, kbb, nullptr, kM, 2048, 2048);
  mixf_k<<<mgrid, blk, 0, stream>>>(t5, w2t, x, shift, maav, xmix, 2);
  gemm_k<128, 128, E_BF16><<<dim3(kM / 128, 16), blk, 0, stream>>>(xmix, Wvt, vbb, nullptr, kM, 2048, 2048);
  mixf_k<<<mgrid, blk, 0, stream>>>(t5, w2t, x, shift, maar, xmix, 3);
  gemm_k<128, 128, E_BF16><<<dim3(kM / 128, 16), blk, 0, stream>>>(xmix, Wrt, rbb, nullptr, kM, 2048, 2048);

  // WKV: pass1 local states (Wrt/Wkt region now dead) -> combine -> pass2 outputs
  wkv_local_k<<<dim3(kB * kH * SEGN), blk, 0, stream>>>(kbb, vbb, edec, Lbuf, DsegP);
  wkv_combine_k<<<dim3(kB * kH), blk, 0, stream>>>(s0, DsegP, Lbuf, stOut);
  wkv_seg_k<<<dim3(kB * kH * SEGN), blk, 0, stream>>>(rbb, kbb, vbb, edec, faaaa, Lbuf, obf);

  // g path (after wkv so xg reuses edec region, g reuses r region)
  mixf_k<<<mgrid, blk, 0, stream>>>(t5, w2t, x, shift, maag, xg, 4);
  gemm_k<128, 128, E_SILU><<<dim3(kM / 128, 16), blk, 0, stream>>>(xg, Wgt, gbb, nullptr, kM, 2048, 2048);

  // groupnorm * g -> bf16 (y reuses k region)
  gn_k<<<dim3(kM * kH / 4), blk, 0, stream>>>(obf, gbb, gnw, gnb, ybuf);

  // out = y @ Wo -> d_out
  gemm_k<128, 128, E_F32><<<dim3(kM / 128, 16), blk, 0, stream>>>(ybuf, Wot, outp, nullptr, kM, 2048, 2048);
}

// Round 6
// 1533.186 us; speedup vs baseline: 3.1260x; 1.2252x over previous
//
#include <hip/hip_runtime.h>
#include <hip/hip_bf16.h>
#include <stdint.h>

#define DEV __device__ __forceinline__

typedef __bf16 bf16x8 __attribute__((ext_vector_type(8)));
typedef float f32x4 __attribute__((ext_vector_type(4)));
typedef unsigned short u16x8 __attribute__((ext_vector_type(8)));

constexpr int kB = 4, kT = 4096, kC = 2048, kH = 32, kN = 64;
constexpr int kM = kB * kT; // 16384
constexpr int SEGN = 8, TSEG = kT / SEGN, CHN = TSEG / 64; // 8 segments x 512 t x 8 chunks

// ---------- bf16 helpers (raw ushort storage everywhere) ----------
DEV float bfu2f(unsigned short u) {
  union { uint32_t i; float f; } x; x.i = ((uint32_t)u) << 16; return x.f;
}
DEV unsigned short f2bfu(float f) {
  union { float f; uint32_t i; } x; x.f = f;
  uint32_t r = x.i + 0x7FFFu + ((x.i >> 16) & 1u);
  return (unsigned short)(r >> 16);
}

// ---------- async global->LDS (16B per lane, wave-uniform LDS base) ----------
DEV void gld16(const void* g, void* l) {
  __builtin_amdgcn_global_load_lds(
      (const __attribute__((address_space(1))) void*)g,
      (__attribute__((address_space(3))) void*)l, 16, 0, 0);
}

// swizzled byte offset within a [rows][128B] LDS tile (row-major, 64 bf16/row)
DEV int swzb(int row, int byteoff) { return (row << 7) + (byteoff ^ ((row & 7) << 4)); }

// ---------- generic transpose + fp32->bf16:  out[c][r] = bf16(in[r][c]) ----------
__global__ __launch_bounds__(256) void trans_bf16(
    const float* __restrict__ in, unsigned short* __restrict__ out, int R, int Cn) {
  __shared__ __attribute__((aligned(16))) unsigned short tile[64][65];
  const int t = threadIdx.x;
  const int r0 = blockIdx.y * 64, c0 = blockIdx.x * 64;
  const int lr = t >> 6, lc = t & 63;
#pragma unroll
  for (int i = 0; i < 16; i++) {
    int rr = lr + i * 4;
    int gr = r0 + rr, gc = c0 + lc;
    if (gr < R && gc < Cn) tile[rr][lc] = f2bfu(in[(size_t)gr * Cn + gc]);
  }
  __syncthreads();
#pragma unroll
  for (int i = 0; i < 16; i++) {
    int cc = lr + i * 4;
    int gc = c0 + cc, gr = r0 + lc;
    if (gc < Cn && gr < R) out[(size_t)gc * R + gr] = tile[lc][cc];
  }
}

// ---------- prep: xxx = bf16(x + (shift(x)-x)*maa_x), lx copy ----------
__global__ __launch_bounds__(256) void prep_x2(
    const float* __restrict__ x, const float* __restrict__ shift,
    const float* __restrict__ maax,
    unsigned short* __restrict__ xxx, float* __restrict__ lx) {
  size_t i4 = ((size_t)blockIdx.x * 256 + threadIdx.x) * 4;
  int c = (int)(i4 & (kC - 1));
  size_t bt = i4 >> 11;           // /C
  int tt = (int)(bt & (kT - 1));
  int b = (int)(bt >> 12);        // /T
  float4 xv = *(const float4*)(x + i4);
  float4 pv = (tt == 0) ? *(const float4*)(shift + (size_t)b * kC + c)
                        : *(const float4*)(x + i4 - kC);
  float4 mx = *(const float4*)(maax + c);
  ushort4 o4;
  o4.x = f2bfu(xv.x + (pv.x - xv.x) * mx.x);
  o4.y = f2bfu(xv.y + (pv.y - xv.y) * mx.y);
  o4.z = f2bfu(xv.z + (pv.z - xv.z) * mx.z);
  o4.w = f2bfu(xv.w + (pv.w - xv.w) * mx.w);
  *(ushort4*)(xxx + i4) = o4;
  if (tt == kT - 1) *(float4*)(lx + (size_t)b * kC + c) = xv;
}

enum { E_F32 = 0, E_BF16 = 1, E_TANH = 2, E_SILU = 3, E_DECAY = 4 };

// ---------- small-shape bf16 MFMA GEMM (m97-style 128-tile), kept for odd shapes ----------
template <int BM, int BN, int EPI>
__global__ __launch_bounds__(256) void gemm_k(
    const unsigned short* __restrict__ A, const unsigned short* __restrict__ Bt,
    void* __restrict__ Cout, const float* __restrict__ aux, int M, int N, int K) {
  constexpr int WGM = (BM == 128 && BN == 128) ? 2 : (BM == 64 ? 2 : 4);
  constexpr int WGN = 4 / WGM;
  constexpr int WM = BM / WGM, WN = BN / WGN;
  constexpr int WR = WM / 16, WC = WN / 16;
  __shared__ __attribute__((aligned(16))) unsigned short As[BM * 32];
  __shared__ __attribute__((aligned(16))) unsigned short Bs[BN * 32];
  const int t = threadIdx.x, wid = t >> 6, l = t & 63;
  const int m0 = blockIdx.x * BM, n0 = blockIdx.y * BN;
  const int wm0 = (wid / WGN) * WM, wn0 = (wid % WGN) * WN;
  f32x4 acc[WR][WC];
#pragma unroll
  for (int i = 0; i < WR; i++)
#pragma unroll
    for (int j = 0; j < WC; j++) acc[i][j] = f32x4{0.f, 0.f, 0.f, 0.f};

  const int rowS = t >> 2, cbS = (t & 3) * 16;
  const char* Ab = (const char*)A;
  const char* Bb = (const char*)Bt;
  const int aoff = (wm0 + (l & 15)) * 32 + (l >> 4) * 8;
  const int boff = (wn0 + (l & 15)) * 32 + (l >> 4) * 8;

  for (int kt = 0; kt < K; kt += 32) {
#pragma unroll
    for (int ia = 0; ia < BM / 64; ia++)
      gld16(Ab + ((size_t)(m0 + ia * 64 + rowS) * K + kt) * 2 + cbS,
            (char*)As + ia * 4096 + wid * 1024);
    if constexpr (BN >= 64) {
#pragma unroll
      for (int ib = 0; ib < BN / 64; ib++)
        gld16(Bb + ((size_t)(n0 + ib * 64 + rowS) * K + kt) * 2 + cbS,
              (char*)Bs + ib * 4096 + wid * 1024);
    } else {
      if (t < BN * 4)
        gld16(Bb + ((size_t)(n0 + rowS) * K + kt) * 2 + cbS,
              (char*)Bs + wid * 1024);
    }
    __syncthreads();
    bf16x8 af[WR], bfv[WC];
#pragma unroll
    for (int mi = 0; mi < WR; mi++) af[mi] = *(const bf16x8*)(&As[aoff + mi * 512]);
#pragma unroll
    for (int ni = 0; ni < WC; ni++) bfv[ni] = *(const bf16x8*)(&Bs[boff + ni * 512]);
#pragma unroll
    for (int mi = 0; mi < WR; mi++)
#pragma unroll
      for (int ni = 0; ni < WC; ni++)
        acc[mi][ni] = __builtin_amdgcn_mfma_f32_16x16x32_bf16(af[mi], bfv[ni], acc[mi][ni], 0, 0, 0);
    __syncthreads();
  }

#pragma unroll
  for (int mi = 0; mi < WR; mi++) {
#pragma unroll
    for (int ni = 0; ni < WC; ni++) {
      int row = m0 + wm0 + mi * 16 + (l >> 4) * 4;
      int col = n0 + wn0 + ni * 16 + (l & 15);
#pragma unroll
      for (int j = 0; j < 4; j++) {
        float v = acc[mi][ni][j];
        size_t idx = (size_t)(row + j) * N + col;
        if constexpr (EPI == E_F32) ((float*)Cout)[idx] = v;
        else if constexpr (EPI == E_BF16) ((unsigned short*)Cout)[idx] = f2bfu(v);
        else if constexpr (EPI == E_TANH) ((unsigned short*)Cout)[idx] = f2bfu(tanhf(v));
        else if constexpr (EPI == E_SILU) ((unsigned short*)Cout)[idx] = f2bfu(v / (1.f + expf(-v)));
        else if constexpr (EPI == E_DECAY) {
          float w = v + aux[col];
          ((float*)Cout)[idx] = expf(-expf(w));
        }
      }
    }
  }
}

// ---------- big GEMM: 256x256 tile, BK=64, 8 waves, dbuf + prefetch + T2 swizzle ----------
// stage one full K-tile (A and B halves) into LDS at byte offsets aoff/boff;
// linear LDS dest, pre-swizzled global source (rule #21: both-sides-or-neither)
DEV void stage256(const unsigned short* A, const unsigned short* Bt,
                  char* lds, int aoff, int boff, int m0, int n0, int K, int kt,
                  int tid, int wid) {
#pragma unroll
  for (int i = 0; i < 4; i++) {
    int row = i * 64 + (tid >> 3);
    int cb = ((tid & 7) * 16) ^ ((row & 7) << 4);
    gld16((const char*)A + ((size_t)(m0 + row) * K + kt) * 2 + cb,
          lds + aoff + i * 8192 + wid * 1024);
    gld16((const char*)Bt + ((size_t)(n0 + row) * K + kt) * 2 + cb,
          lds + boff + i * 8192 + wid * 1024);
  }
}

template <int EPI>
__global__ __launch_bounds__(512, 2) void gemm256_k(
    const unsigned short* __restrict__ A, const unsigned short* __restrict__ Bt,
    void* __restrict__ Cout, int M, int N, int K) {
  extern __shared__ __attribute__((aligned(16))) char lds[];
  const int tid = threadIdx.x, wid = tid >> 6, l = tid & 63;

  // T1: bijective XCD swizzle (nwg % 8 == 0 for all our shapes)
  const int nwg = gridDim.x, cpx = nwg >> 3;
  int swz = (blockIdx.x & 7) * cpx + (blockIdx.x >> 3);
  const int mtiles = M >> 8;
  const int m0 = (swz % mtiles) * 256, n0 = (swz / mtiles) * 256;

  const int wm = (wid >> 2) * 128, wn = (wid & 3) * 64;
  f32x4 acc[8][4];
#pragma unroll
  for (int i = 0; i < 8; i++)
#pragma unroll
    for (int j = 0; j < 4; j++) acc[i][j] = f32x4{0.f, 0.f, 0.f, 0.f};

  const int KT = K >> 6;
  stage256(A, Bt, lds, 0, 65536, m0, n0, K, 0, tid, wid);
  __syncthreads();
  int cur = 0;

  for (int t = 0; t < KT; ++t) {
    if (t + 1 < KT)
      stage256(A, Bt, lds, (cur ^ 1) * 32768, 65536 + (cur ^ 1) * 32768,
               m0, n0, K, (t + 1) * 64, tid, wid);
    const char* Ab = lds + cur * 32768;
    const char* Bb = lds + 65536 + cur * 32768;
    __builtin_amdgcn_s_setprio(1);
#pragma unroll
    for (int ks = 0; ks < 2; ks++) {
      bf16x8 a[8];
#pragma unroll
      for (int mi = 0; mi < 8; mi++)
        a[mi] = *(const bf16x8*)(Ab + swzb(wm + mi * 16 + (l & 15), ks * 64 + (l >> 4) * 16));
#pragma unroll
      for (int ni = 0; ni < 4; ni++) {
        bf16x8 b = *(const bf16x8*)(Bb + swzb(wn + ni * 16 + (l & 15), ks * 64 + (l >> 4) * 16));
#pragma unroll
        for (int mi = 0; mi < 8; mi++)
          acc[mi][ni] = __builtin_amdgcn_mfma_f32_16x16x32_bf16(a[mi], b, acc[mi][ni], 0, 0, 0);
      }
    }
    __builtin_amdgcn_s_setprio(0);
    __syncthreads();   // drains vmcnt (stage done) + all waves' reads done
    cur ^= 1;
  }

#pragma unroll
  for (int mi = 0; mi < 8; mi++)
#pragma unroll
    for (int ni = 0; ni < 4; ni++) {
      int row = m0 + wm + mi * 16 + (l >> 4) * 4;
      int col = n0 + wn + ni * 16 + (l & 15);
#pragma unroll
      for (int j = 0; j < 4; j++) {
        float v = acc[mi][ni][j];
        size_t idx = (size_t)(row + j) * N + col;
        if constexpr (EPI == E_F32) ((float*)Cout)[idx] = v;
        else if constexpr (EPI == E_BF16) ((unsigned short*)Cout)[idx] = f2bfu(v);
        else if constexpr (EPI == E_SILU) ((unsigned short*)Cout)[idx] = f2bfu(v / (1.f + expf(-v)));
      }
    }
}

// ---------- single-feature mix:  m = t5[:,f*32:(f+1)*32] @ w2t[:,f*32:(f+1)*32]^T
//            xout = bf16( x + (shift(x)-x) * (maa + m) )
__global__ __launch_bounds__(256) void mixf_k(
    const unsigned short* __restrict__ t5, const unsigned short* __restrict__ w2t,
    const float* __restrict__ x, const float* __restrict__ shift,
    const float* __restrict__ maa, unsigned short* __restrict__ xout, int f) {
  __shared__ __attribute__((aligned(16))) unsigned short As[64 * 32];
  __shared__ __attribute__((aligned(16))) unsigned short Bs[64 * 32];
  const int t = threadIdx.x, wid = t >> 6, l = t & 63;
  const int m0 = blockIdx.x * 64, n0 = blockIdx.y * 64;
  const int wm0 = (wid >> 1) * 32, wn0 = (wid & 1) * 32;
  const int rowS = t >> 2, cbS = (t & 3) * 16;
  const int aoff = (wm0 + (l & 15)) * 32 + (l >> 4) * 8;
  const int boff = (wn0 + (l & 15)) * 32 + (l >> 4) * 8;

  gld16((const char*)t5 + ((size_t)(m0 + rowS) * 160 + f * 32) * 2 + cbS, (char*)As + wid * 1024);
  gld16((const char*)w2t + ((size_t)(n0 + rowS) * 160 + f * 32) * 2 + cbS, (char*)Bs + wid * 1024);
  __syncthreads();
  bf16x8 a0 = *(const bf16x8*)(&As[aoff]), a1 = *(const bf16x8*)(&As[aoff + 512]);
  bf16x8 b0 = *(const bf16x8*)(&Bs[boff]), b1 = *(const bf16x8*)(&Bs[boff + 512]);
  f32x4 acc[2][2];
  acc[0][0] = f32x4{0.f, 0.f, 0.f, 0.f}; acc[0][1] = f32x4{0.f, 0.f, 0.f, 0.f};
  acc[1][0] = f32x4{0.f, 0.f, 0.f, 0.f}; acc[1][1] = f32x4{0.f, 0.f, 0.f, 0.f};
  acc[0][0] = __builtin_amdgcn_mfma_f32_16x16x32_bf16(a0, b0, acc[0][0], 0, 0, 0);
  acc[0][1] = __builtin_amdgcn_mfma_f32_16x16x32_bf16(a0, b1, acc[0][1], 0, 0, 0);
  acc[1][0] = __builtin_amdgcn_mfma_f32_16x16x32_bf16(a1, b0, acc[1][0], 0, 0, 0);
  acc[1][1] = __builtin_amdgcn_mfma_f32_16x16x32_bf16(a1, b1, acc[1][1], 0, 0, 0);

#pragma unroll
  for (int mi = 0; mi < 2; mi++)
#pragma unroll
    for (int ni = 0; ni < 2; ni++) {
      int row = m0 + wm0 + mi * 16 + (l >> 4) * 4;
      int col = n0 + wn0 + ni * 16 + (l & 15);
      float mv = maa[col];
#pragma unroll
      for (int j = 0; j < 4; j++) {
        int rrow = row + j;
        int tt = rrow & (kT - 1);
        size_t idx = (size_t)rrow * kC + col;
        float xv = x[idx];
        float pv = (tt == 0) ? shift[(size_t)(rrow >> 12) * kC + col] : x[idx - kC];
        xout[idx] = f2bfu(xv + (pv - xv) * (mv + acc[mi][ni][j]));
      }
    }
}

// ---------- WKV pass 1: per-segment local state (zero init) + decay product ----------
__global__ __launch_bounds__(256) void wkv_local_k(
    const unsigned short* __restrict__ kb, const unsigned short* __restrict__ vb,
    const float* __restrict__ ed, float* __restrict__ Lbuf, float* __restrict__ Dseg) {
  const int bid = blockIdx.x;            // bh*SEGN + seg
  const int bh = bid >> 3, seg = bid & 7;
  const int h = bh & 31, b = bh >> 5;
  const int tid = threadIdx.x, w = tid >> 6, l = tid & 63;
  __shared__ __attribute__((aligned(16))) unsigned short KQks[4096]; // [k][s] swz
  __shared__ __attribute__((aligned(16))) unsigned short Vt[4096];   // [v][s] swz
  __shared__ __attribute__((aligned(16))) float Sf[64][68];
  __shared__ float segp[4][64];
  __shared__ float DLs[64];

  const int fr = l & 15, fq = l >> 4;
#pragma unroll
  for (int ni = 0; ni < 4; ni++)
#pragma unroll
    for (int j = 0; j < 4; j++) Sf[w * 16 + fq * 4 + j][ni * 16 + fr] = 0.f;

  float dtot = 1.f;
  float kv[16], dv[16], vv[16];
  {
    size_t g = ((size_t)b * kT + seg * TSEG + w * 16) * kC + h * 64 + l;
#pragma unroll
    for (int i = 0; i < 16; i++) {
      kv[i] = bfu2f(kb[g]); vv[i] = bfu2f(vb[g]); dv[i] = ed[g];
      g += kC;
    }
  }

  for (int ch = 0; ch < CHN; ++ch) {
    float p = 1.f;
#pragma unroll
    for (int i = 0; i < 16; i++) p *= dv[i];
    segp[w][l] = p;
    __syncthreads();
    float pre = 1.f;
    if (w > 0) pre *= segp[0][l];
    if (w > 1) pre *= segp[1][l];
    if (w > 2) pre *= segp[2][l];
    if (w == 3) DLs[l] = pre * p;

    unsigned short kqrow[16], vtrow[16];
    float run = pre;
#pragma unroll
    for (int i = 0; i < 16; i++) {
      run *= dv[i];
      kqrow[i] = f2bfu(kv[i] / run);
      vtrow[i] = f2bfu(vv[i]);
    }
    {
      u16x8 q0, q1, v0, v1;
#pragma unroll
      for (int j = 0; j < 8; j++) { q0[j] = kqrow[j]; q1[j] = kqrow[j + 8]; v0[j] = vtrow[j]; v1[j] = vtrow[j + 8]; }
      *(u16x8*)((char*)KQks + swzb(l, w * 32)) = q0;
      *(u16x8*)((char*)KQks + swzb(l, w * 32 + 16)) = q1;
      *(u16x8*)((char*)Vt + swzb(l, w * 32)) = v0;
      *(u16x8*)((char*)Vt + swzb(l, w * 32 + 16)) = v1;
    }
    if (ch < CHN - 1) {
      size_t g = ((size_t)b * kT + seg * TSEG + (ch + 1) * 64 + w * 16) * kC + h * 64 + l;
#pragma unroll
      for (int i = 0; i < 16; i++) {
        kv[i] = bfu2f(kb[g]); vv[i] = bfu2f(vb[g]); dv[i] = ed[g];
        g += kC;
      }
    }
    __syncthreads();

    bf16x8 kA0 = *(const bf16x8*)((const char*)KQks + swzb(w * 16 + fr, fq * 16));
    bf16x8 kA1 = *(const bf16x8*)((const char*)KQks + swzb(w * 16 + fr, fq * 16 + 64));
    f32x4 kvacc[4];
#pragma unroll
    for (int ni = 0; ni < 4; ni++) {
      bf16x8 bv0 = *(const bf16x8*)((const char*)Vt + swzb(ni * 16 + fr, fq * 16));
      bf16x8 bv1 = *(const bf16x8*)((const char*)Vt + swzb(ni * 16 + fr, fq * 16 + 64));
      kvacc[ni] = __builtin_amdgcn_mfma_f32_16x16x32_bf16(kA0, bv0, f32x4{0.f, 0.f, 0.f, 0.f}, 0, 0, 0);
      kvacc[ni] = __builtin_amdgcn_mfma_f32_16x16x32_bf16(kA1, bv1, kvacc[ni], 0, 0, 0);
    }
    float dlj[4];
#pragma unroll
    for (int j = 0; j < 4; j++) dlj[j] = DLs[w * 16 + fq * 4 + j];
#pragma unroll
    for (int ni = 0; ni < 4; ni++)
#pragma unroll
      for (int j = 0; j < 4; j++) {
        int kk2 = w * 16 + fq * 4 + j, vv2 = ni * 16 + fr;
        Sf[kk2][vv2] = (Sf[kk2][vv2] + kvacc[ni][j]) * dlj[j];
      }
    dtot *= DLs[l];
    __syncthreads();
  }

  float* Lp = Lbuf + (size_t)bid * 4096;
#pragma unroll
  for (int ni = 0; ni < 4; ni++)
#pragma unroll
    for (int j = 0; j < 4; j++)
      Lp[(size_t)(w * 16 + fq * 4 + j) * 64 + ni * 16 + fr] = Sf[w * 16 + fq * 4 + j][ni * 16 + fr];
  if (w == 0) Dseg[(size_t)bid * 64 + l] = dtot;
}

// ---------- WKV combine: Sini[i] = scan of (Dseg, L); in-place L -> Sini; final -> sOut ----------
__global__ __launch_bounds__(256) void wkv_combine_k(
    const float* __restrict__ s0, const float* __restrict__ Dseg,
    float* __restrict__ Lbuf, float* __restrict__ sOut) {
  const int bh = blockIdx.x, tid = threadIdx.x;
  const int k = tid >> 2, v0 = (tid & 3) * 16;
  float4 s[4];
  const float* sp = s0 + (size_t)bh * 4096 + (size_t)k * 64 + v0;
#pragma unroll
  for (int q = 0; q < 4; q++) s[q] = ((const float4*)sp)[q];
  for (int seg = 0; seg < SEGN; ++seg) {
    size_t idx = (size_t)bh * SEGN + seg;
    float d = Dseg[idx * 64 + k];
    float* Lp = Lbuf + idx * 4096 + (size_t)k * 64 + v0;
#pragma unroll
    for (int q = 0; q < 4; q++) {
      float4 lq = ((float4*)Lp)[q];
      ((float4*)Lp)[q] = s[q];
      s[q].x = d * s[q].x + lq.x; s[q].y = d * s[q].y + lq.y;
      s[q].z = d * s[q].z + lq.z; s[q].w = d * s[q].w + lq.w;
    }
  }
  float* op = sOut + (size_t)bh * 4096 + (size_t)k * 64 + v0;
#pragma unroll
  for (int q = 0; q < 4; q++) ((float4*)op)[q] = s[q];
}

// ---------- WKV pass 2: per-segment full output pipeline (init from Sini) ----------
__global__ __launch_bounds__(256) void wkv_seg_k(
    const unsigned short* __restrict__ rb, const unsigned short* __restrict__ kb,
    const unsigned short* __restrict__ vb, const float* __restrict__ ed,
    const float* __restrict__ uf, const float* __restrict__ Sini,
    unsigned short* __restrict__ o) {
  const int bid = blockIdx.x;            // bh*SEGN + seg
  const int bh = bid >> 3, seg = bid & 7;
  const int h = bh & 31, b = bh >> 5;
  const int tid = threadIdx.x, w = tid >> 6, l = tid & 63;
  __shared__ __attribute__((aligned(16))) unsigned short RQ[4096];   // [t][k] swz bf16
  __shared__ __attribute__((aligned(16))) unsigned short KQsk[4096]; // [s][k] swz
  __shared__ __attribute__((aligned(16))) unsigned short KQks[4096]; // [k][s] swz
  __shared__ __attribute__((aligned(16))) unsigned short Vt[4096];   // [v][s] swz
  __shared__ __attribute__((aligned(16))) unsigned short Pl[4096];   // [t][s] swz
  __shared__ __attribute__((aligned(16))) unsigned short S0T[4096];  // [v][k] swz
  __shared__ __attribute__((aligned(16))) float Sf[64][68];          // fp32 master state
  __shared__ float segp[4][64];
  __shared__ float DLs[64];
  __shared__ float diag[64];

  const float uu = uf[h * 64 + l];

  {
    int k0 = tid >> 2, vs = (tid & 3) << 4;
    const float* sp = Sini + (size_t)bid * 4096 + (size_t)k0 * 64 + vs;
#pragma unroll
    for (int q = 0; q < 4; q++) {
      float4 f4 = ((const float4*)sp)[q];
      int v = vs + q * 4;
      Sf[k0][v + 0] = f4.x; Sf[k0][v + 1] = f4.y; Sf[k0][v + 2] = f4.z; Sf[k0][v + 3] = f4.w;
      *(unsigned short*)((char*)S0T + swzb(v + 0, k0 * 2)) = f2bfu(f4.x);
      *(unsigned short*)((char*)S0T + swzb(v + 1, k0 * 2)) = f2bfu(f4.y);
      *(unsigned short*)((char*)S0T + swzb(v + 2, k0 * 2)) = f2bfu(f4.z);
      *(unsigned short*)((char*)S0T + swzb(v + 3, k0 * 2)) = f2bfu(f4.w);
    }
  }
  __syncthreads();

  const int fr = l & 15, fq = l >> 4;
  float rv[16], kv[16], dv[16], vv[16];

  {
    size_t g = ((size_t)b * kT + seg * TSEG + w * 16) * kC + h * 64 + l;
#pragma unroll
    for (int i = 0; i < 16; i++) {
      rv[i] = bfu2f(rb[g]); kv[i] = bfu2f(kb[g]); vv[i] = bfu2f(vb[g]); dv[i] = ed[g];
      g += kC;
    }
  }

  for (int ch = 0; ch < CHN; ++ch) {
    float p = 1.f;
#pragma unroll
    for (int i = 0; i < 16; i++) p *= dv[i];
    segp[w][l] = p;
    __syncthreads();
    float pre = 1.f;
    if (w > 0) pre *= segp[0][l];
    if (w > 1) pre *= segp[1][l];
    if (w > 2) pre *= segp[2][l];
    if (w == 3) DLs[l] = pre * p;

    unsigned short kqrow[16], vtrow[16];
    float run = pre;
#pragma unroll
    for (int i = 0; i < 16; i++) {
      int t = w * 16 + i;
      float rq = rv[i] * run;
      run *= dv[i];
      float kq = kv[i] / run;
      *(unsigned short*)((char*)RQ + swzb(t, l * 2)) = f2bfu(rq);
      unsigned short kqu = f2bfu(kq);
      *(unsigned short*)((char*)KQsk + swzb(t, l * 2)) = kqu;
      kqrow[i] = kqu;
      vtrow[i] = f2bfu(vv[i]);
    }
    {
      u16x8 q0, q1, v0, v1;
#pragma unroll
      for (int j = 0; j < 8; j++) { q0[j] = kqrow[j]; q1[j] = kqrow[j + 8]; v0[j] = vtrow[j]; v1[j] = vtrow[j + 8]; }
      *(u16x8*)((char*)KQks + swzb(l, w * 32)) = q0;
      *(u16x8*)((char*)KQks + swzb(l, w * 32 + 16)) = q1;
      *(u16x8*)((char*)Vt + swzb(l, w * 32)) = v0;
      *(u16x8*)((char*)Vt + swzb(l, w * 32 + 16)) = v1;
    }
#pragma unroll
    for (int i = 0; i < 16; i++) {
      float dsv = rv[i] * uu * kv[i];
#pragma unroll
      for (int m = 1; m < 64; m <<= 1) dsv += __shfl_xor(dsv, m, 64);
      if (l == 0) diag[w * 16 + i] = dsv;
    }

    if (ch < CHN - 1) {
      size_t g = ((size_t)b * kT + seg * TSEG + (ch + 1) * 64 + w * 16) * kC + h * 64 + l;
#pragma unroll
      for (int i = 0; i < 16; i++) {
        rv[i] = bfu2f(rb[g]); kv[i] = bfu2f(kb[g]); vv[i] = bfu2f(vb[g]); dv[i] = ed[g];
        g += kC;
      }
    }
    __syncthreads();

    bf16x8 a0 = *(const bf16x8*)((const char*)RQ + swzb(w * 16 + fr, fq * 16));
    bf16x8 a1 = *(const bf16x8*)((const char*)RQ + swzb(w * 16 + fr, fq * 16 + 64));
    f32x4 pacc[4];
#pragma unroll
    for (int ni = 0; ni < 4; ni++) {
      bf16x8 b0 = *(const bf16x8*)((const char*)KQsk + swzb(ni * 16 + fr, fq * 16));
      bf16x8 b1 = *(const bf16x8*)((const char*)KQsk + swzb(ni * 16 + fr, fq * 16 + 64));
      pacc[ni] = __builtin_amdgcn_mfma_f32_16x16x32_bf16(a0, b0, f32x4{0.f, 0.f, 0.f, 0.f}, 0, 0, 0);
      pacc[ni] = __builtin_amdgcn_mfma_f32_16x16x32_bf16(a1, b1, pacc[ni], 0, 0, 0);
    }
    float dg[4];
#pragma unroll
    for (int j = 0; j < 4; j++) dg[j] = diag[w * 16 + fq * 4 + j];
#pragma unroll
    for (int ni = 0; ni < 4; ni++)
#pragma unroll
      for (int j = 0; j < 4; j++) {
        int row = w * 16 + fq * 4 + j, col = ni * 16 + fr;
        float pv = pacc[ni][j];
        pv = (col < row) ? pv : ((col == row) ? dg[j] : 0.f);
        *(unsigned short*)((char*)Pl + swzb(row, col * 2)) = f2bfu(pv);
      }
    __syncthreads();

    bf16x8 pA0 = *(const bf16x8*)((const char*)Pl + swzb(w * 16 + fr, fq * 16));
    bf16x8 pA1 = *(const bf16x8*)((const char*)Pl + swzb(w * 16 + fr, fq * 16 + 64));
    bf16x8 kA0 = *(const bf16x8*)((const char*)KQks + swzb(w * 16 + fr, fq * 16));
    bf16x8 kA1 = *(const bf16x8*)((const char*)KQks + swzb(w * 16 + fr, fq * 16 + 64));
    f32x4 oacc[4], kvacc[4];
#pragma unroll
    for (int ni = 0; ni < 4; ni++) {
      bf16x8 bv0 = *(const bf16x8*)((const char*)Vt + swzb(ni * 16 + fr, fq * 16));
      bf16x8 bv1 = *(const bf16x8*)((const char*)Vt + swzb(ni * 16 + fr, fq * 16 + 64));
      bf16x8 bs0 = *(const bf16x8*)((const char*)S0T + swzb(ni * 16 + fr, fq * 16));
      bf16x8 bs1 = *(const bf16x8*)((const char*)S0T + swzb(ni * 16 + fr, fq * 16 + 64));
      oacc[ni] = __builtin_amdgcn_mfma_f32_16x16x32_bf16(pA0, bv0, f32x4{0.f, 0.f, 0.f, 0.f}, 0, 0, 0);
      oacc[ni] = __builtin_amdgcn_mfma_f32_16x16x32_bf16(pA1, bv1, oacc[ni], 0, 0, 0);
      oacc[ni] = __builtin_amdgcn_mfma_f32_16x16x32_bf16(a0, bs0, oacc[ni], 0, 0, 0);
      oacc[ni] = __builtin_amdgcn_mfma_f32_16x16x32_bf16(a1, bs1, oacc[ni], 0, 0, 0);
      kvacc[ni] = __builtin_amdgcn_mfma_f32_16x16x32_bf16(kA0, bv0, f32x4{0.f, 0.f, 0.f, 0.f}, 0, 0, 0);
      kvacc[ni] = __builtin_amdgcn_mfma_f32_16x16x32_bf16(kA1, bv1, kvacc[ni], 0, 0, 0);
    }
    size_t obase = ((size_t)b * kT + seg * TSEG + ch * 64) * kC + h * 64;
#pragma unroll
    for (int ni = 0; ni < 4; ni++)
#pragma unroll
      for (int j = 0; j < 4; j++)
        o[obase + (size_t)(w * 16 + fq * 4 + j) * kC + ni * 16 + fr] = f2bfu(oacc[ni][j]);
    __syncthreads();

    float dlj[4];
#pragma unroll
    for (int j = 0; j < 4; j++) dlj[j] = DLs[w * 16 + fq * 4 + j];
#pragma unroll
    for (int ni = 0; ni < 4; ni++)
#pragma unroll
      for (int j = 0; j < 4; j++) {
        int kk2 = w * 16 + fq * 4 + j, vv2 = ni * 16 + fr;
        float sn = (Sf[kk2][vv2] + kvacc[ni][j]) * dlj[j];
        Sf[kk2][vv2] = sn;
        *(unsigned short*)((char*)S0T + swzb(vv2, kk2 * 2)) = f2bfu(sn);
      }
    __syncthreads();
  }
}

// ---------- GroupNorm over N=64 per (b,t,h), times g, -> bf16 ----------
__global__ __launch_bounds__(256) void gn_k(
    const unsigned short* __restrict__ o, const unsigned short* __restrict__ gb,
    const float* __restrict__ gnw, const float* __restrict__ gnb,
    unsigned short* __restrict__ y) {
  int gi = blockIdx.x * 4 + (threadIdx.x >> 6);
  int j = threadIdx.x & 63;
  int bt = gi >> 5, h = gi & 31;
  size_t idx = (size_t)bt * kC + h * 64 + j;
  float val = bfu2f(o[idx]);
  float s = val, s2 = val * val;
#pragma unroll
  for (int m = 1; m < 64; m <<= 1) {
    s += __shfl_xor(s, m, 64);
    s2 += __shfl_xor(s2, m, 64);
  }
  float mu = s * 0.015625f;
  float var = s2 * 0.015625f - mu * mu;
  float rs = rsqrtf(var + 6.4e-4f);
  float on = (val - mu) * rs * gnw[h * 64 + j] + gnb[h * 64 + j];
  y[idx] = f2bfu(on * bfu2f(gb[idx]));
}

// ---------- workspace layout (peak ~433 MiB) ----------
constexpr size_t SZW     = (size_t)2048 * 2048 * 2;              // 8 MiB bf16 weight
constexpr size_t OFF_WRT = 0;
constexpr size_t OFF_WKT = 1 * SZW;
constexpr size_t OFF_WVT = 2 * SZW;
constexpr size_t OFF_WGT = 3 * SZW;
constexpr size_t OFF_WOT = 4 * SZW;
constexpr size_t OFF_W1T = 5 * SZW;                              // [160][2048] bf16
constexpr size_t OFF_W2T = OFF_W1T + (size_t)160 * 2048 * 2;     // [2048][160] bf16
constexpr size_t OFF_TD1 = OFF_W2T + (size_t)2048 * 160 * 2;     // [64][2048] bf16; later Dseg f32
constexpr size_t OFF_TD2 = OFF_TD1 + (size_t)64 * 2048 * 2;      // [2048][64] bf16
constexpr size_t OFF_T5  = OFF_TD2 + (size_t)2048 * 64 * 2;      // [M][160] bf16
constexpr size_t OFF_DT  = OFF_T5 + (size_t)kM * 160 * 2;        // [M][64] bf16 (dtmp)
constexpr size_t OFF_EDEC= OFF_DT + (size_t)kM * 64 * 2;         // [M][C] f32 edec; later xg bf16
constexpr size_t OFF_XMIX= OFF_EDEC + (size_t)kM * kC * 4;       // xxx/xw/xk/xv/xr bf16; later o bf16
constexpr size_t OFF_R   = OFF_XMIX + (size_t)kM * kC * 2;       // r bf16; later g bf16
constexpr size_t OFF_K   = OFF_R + (size_t)kM * kC * 2;          // k bf16; later y bf16
constexpr size_t OFF_V   = OFF_K + (size_t)kM * kC * 2;          // v bf16
constexpr size_t OFF_L   = OFF_WRT;  // L/Sini reuses Wr^T/Wk^T after their GEMMs

extern "C" void kernel_launch(void* const* d_in, const int* in_sizes, int n_in,
                              void* d_out, int out_size, void* d_ws, size_t ws_size,
                              hipStream_t stream) {
  const float* x     = (const float*)d_in[0];
  const float* shift = (const float*)d_in[1];
  const float* s0    = (const float*)d_in[2];
  const float* maax  = (const float*)d_in[3];
  const float* maaw  = (const float*)d_in[4];
  const float* maak  = (const float*)d_in[5];
  const float* maav  = (const float*)d_in[6];
  const float* maar  = (const float*)d_in[7];
  const float* maag  = (const float*)d_in[8];
  const float* w1    = (const float*)d_in[9];
  const float* w2    = (const float*)d_in[10];
  const float* tdec  = (const float*)d_in[11];
  const float* tdw1  = (const float*)d_in[12];
  const float* tdw2  = (const float*)d_in[13];
  const float* faaaa = (const float*)d_in[14];
  const float* Wr    = (const float*)d_in[15];
  const float* Wk    = (const float*)d_in[16];
  const float* Wv    = (const float*)d_in[17];
  const float* Wg    = (const float*)d_in[18];
  const float* Wo    = (const float*)d_in[19];
  const float* gnw   = (const float*)d_in[20];
  const float* gnb   = (const float*)d_in[21];

  char* ws = (char*)d_ws;
  unsigned short* Wrt  = (unsigned short*)(ws + OFF_WRT);
  unsigned short* Wkt  = (unsigned short*)(ws + OFF_WKT);
  unsigned short* Wvt  = (unsigned short*)(ws + OFF_WVT);
  unsigned short* Wgt  = (unsigned short*)(ws + OFF_WGT);
  unsigned short* Wot  = (unsigned short*)(ws + OFF_WOT);
  unsigned short* w1t  = (unsigned short*)(ws + OFF_W1T);
  unsigned short* w2t  = (unsigned short*)(ws + OFF_W2T);
  unsigned short* td1t = (unsigned short*)(ws + OFF_TD1);
  unsigned short* td2t = (unsigned short*)(ws + OFF_TD2);
  unsigned short* t5   = (unsigned short*)(ws + OFF_T5);
  unsigned short* dtmp = (unsigned short*)(ws + OFF_DT);
  float*          edec = (float*)(ws + OFF_EDEC);
  unsigned short* xg   = (unsigned short*)(ws + OFF_EDEC); // after edec dead
  unsigned short* xmix = (unsigned short*)(ws + OFF_XMIX);
  unsigned short* obf  = (unsigned short*)(ws + OFF_XMIX); // after xmix dead
  unsigned short* rbb  = (unsigned short*)(ws + OFF_R);
  unsigned short* gbb  = (unsigned short*)(ws + OFF_R);    // after r dead
  unsigned short* kbb  = (unsigned short*)(ws + OFF_K);
  unsigned short* ybuf = (unsigned short*)(ws + OFF_K);    // after k dead
  unsigned short* vbb  = (unsigned short*)(ws + OFF_V);
  float*          Lbuf = (float*)(ws + OFF_L);             // after Wrt/Wkt dead
  float*          DsegP= (float*)(ws + OFF_TD1);           // after td1t dead

  float* outp  = (float*)d_out;
  float* lx    = outp + (size_t)kM * kC;
  float* stOut = lx + (size_t)kB * kC;

  dim3 blk(256);

  // weight prep (transpose to [N][K] bf16)
  trans_bf16<<<dim3(32, 32), blk, 0, stream>>>(Wr, Wrt, 2048, 2048);
  trans_bf16<<<dim3(32, 32), blk, 0, stream>>>(Wk, Wkt, 2048, 2048);
  trans_bf16<<<dim3(32, 32), blk, 0, stream>>>(Wv, Wvt, 2048, 2048);
  trans_bf16<<<dim3(32, 32), blk, 0, stream>>>(Wg, Wgt, 2048, 2048);
  trans_bf16<<<dim3(32, 32), blk, 0, stream>>>(Wo, Wot, 2048, 2048);
  trans_bf16<<<dim3(3, 32), blk, 0, stream>>>(w1, w1t, 2048, 160);
  trans_bf16<<<dim3(1, 32), blk, 0, stream>>>(tdw1, td1t, 2048, 64);
  trans_bf16<<<dim3(32, 1), blk, 0, stream>>>(tdw2, td2t, 64, 2048);
  trans_bf16<<<dim3(32, 3), blk, 0, stream>>>(w2, w2t, 160, 2048);

  // token shift + maa_x mix (+ lx output)
  prep_x2<<<dim3(kM * kC / 4 / 256), blk, 0, stream>>>(x, shift, maax, xmix, lx);

  // t5 = tanh(xxx @ w1)  -> [M][160]
  gemm_k<128, 32, E_TANH><<<dim3(kM / 128, 5), blk, 0, stream>>>(xmix, w1t, t5, nullptr, kM, 160, 2048);

  dim3 mgrid(kM / 64, kC / 64);
  constexpr int G256 = (kM / 256) * (kC / 256);   // 512 blocks
  constexpr size_t LDS256 = 131072;

  // decay path: xw -> dtmp = tanh(xw @ tdw1); edec = exp(-exp(dtmp @ tdw2 + time_decay))
  mixf_k<<<mgrid, blk, 0, stream>>>(t5, w2t, x, shift, maaw, xmix, 0);
  gemm_k<64, 64, E_TANH><<<dim3(kM / 64, 1), blk, 0, stream>>>(xmix, td1t, dtmp, nullptr, kM, 64, 2048);
  gemm_k<128, 128, E_DECAY><<<dim3(kM / 128, 16), blk, 0, stream>>>(dtmp, td2t, edec, tdec, kM, 2048, 64);

  // k, v, r projections (sequential reuse of xmix) — 256^2 pipelined GEMM
  mixf_k<<<mgrid, blk, 0, stream>>>(t5, w2t, x, shift, maak, xmix, 1);
  gemm256_k<E_BF16><<<dim3(G256), dim3(512), LDS256, stream>>>(xmix, Wkt, kbb, kM, 2048, 2048);
  mixf_k<<<mgrid, blk, 0, stream>>>(t5, w2t, x, shift, maav, xmix, 2);
  gemm256_k<E_BF16><<<dim3(G256), dim3(512), LDS256, stream>>>(xmix, Wvt, vbb, kM, 2048, 2048);
  mixf_k<<<mgrid, blk, 0, stream>>>(t5, w2t, x, shift, maar, xmix, 3);
  gemm256_k<E_BF16><<<dim3(G256), dim3(512), LDS256, stream>>>(xmix, Wrt, rbb, kM, 2048, 2048);

  // WKV: pass1 local states (Wrt/Wkt region now dead) -> combine -> pass2 outputs
  wkv_local_k<<<dim3(kB * kH * SEGN), blk, 0, stream>>>(kbb, vbb, edec, Lbuf, DsegP);
  wkv_combine_k<<<dim3(kB * kH), blk, 0, stream>>>(s0, DsegP, Lbuf, stOut);
  wkv_seg_k<<<dim3(kB * kH * SEGN), blk, 0, stream>>>(rbb, kbb, vbb, edec, faaaa, Lbuf, obf);

  // g path (after wkv so xg reuses edec region, g reuses r region)
  mixf_k<<<mgrid, blk, 0, stream>>>(t5, w2t, x, shift, maag, xg, 4);
  gemm256_k<E_SILU><<<dim3(G256), dim3(512), LDS256, stream>>>(xg, Wgt, gbb, kM, 2048, 2048);

  // groupnorm * g -> bf16 (y reuses k region)
  gn_k<<<dim3(kM * kH / 4), blk, 0, stream>>>(obf, gbb, gnw, gnb, ybuf);

  // out = y @ Wo -> d_out
  gemm256_k<E_F32><<<dim3(G256), dim3(512), LDS256, stream>>>(ybuf, Wot, outp, kM, 2048, 2048);
}